// Round 9
// baseline (1936.738 us; speedup 1.0000x reference)
//
#include <hip/hip_runtime.h>
#include <hip/hip_bf16.h>
#include <math.h>

#define NI 64
#define NC 64
#define NTOK 197
#define TT 196
#define CL 32
#define DD 1024
#define SS 256
#define NN 33
#define EPSN 1e-12f
#define SMOOTHF 9.0f
#define TP 224   // padded token dim for MFMA K

typedef __attribute__((ext_vector_type(8))) short bfrag;
typedef __attribute__((ext_vector_type(4))) float f32x4;
#define MFMA(a, b, c) __builtin_amdgcn_mfma_f32_16x16x32_bf16((a), (b), (c), 0, 0, 0)

// LDS layout (byte offsets) — phase A/W region (dead before SGR)
#define OFF_ATTNT  0        // [32][232] u16 = 14848
#define OFF_WTILE  14848    // [32][136] u16 = 8704 -> 23552
#define OFF_WMAX   23552    // [4][32] f32 = 512 -> 24064
#define OFF_NRMS   24064    // [32] f32 -> 24192
// assembly-time buffers: overlap SGR-only region (dead once SGR starts)
#define OFF_QN     25344    // [128] f32 -> 25856
#define OFF_RNQ    25856    // [32] f32 -> 25984
// SGR overlays
#define OFF_SEA    0        // [48][264] u16 = 25344
#define OFF_EB     25344    // rows 0..32 x 144B = 4752; MFMA reads rows to 47 (alias into R1 head,
                            // garbage only feeds discarded output cols n>=33)
#define OFF_R1     30096    // Gc 48*144=6912 / XT 64*144=9216 / Ef 33*34*4=4488 -> 39312
#define OFF_WKQ    37008    // [256] f32 = 1024 -> 38032 (R1 tail; coexists with Gc only)
#define OFF_VBUF   38032    // [36] f32 = 144 -> 38176 (ditto)
#define SMEM_BYTES 39312

__device__ __forceinline__ float warp_reduce_sum64(float v) {
#pragma unroll
  for (int m = 32; m > 0; m >>= 1) v += __shfl_xor(v, m, 64);
  return v;
}
__device__ __forceinline__ unsigned short f2b(float f) {
  __hip_bfloat16 h = __float2bfloat16(f);
  return *reinterpret_cast<unsigned short*>(&h);
}
__device__ __forceinline__ float b2f(unsigned short u) {
  union { unsigned int i; float f; } v;
  v.i = ((unsigned int)u) << 16;
  return v.f;
}

// ---------------------------------------------------------------- K1: means
__global__ void k_avg(const float* __restrict__ img, const float* __restrict__ cap,
                      float* __restrict__ img_avg, float* __restrict__ cap_avg) {
  int bid = blockIdx.x;
  int tid = threadIdx.x;
  if (bid < NI) {
    int b = bid;
    for (int d = tid; d < DD; d += 256) {
      float acc = 0.f;
      const float* p = img + ((size_t)b * NTOK + 1) * DD + d;
      for (int t = 0; t < TT; ++t) acc += p[(size_t)t * DD];
      img_avg[b * DD + d] = acc * (1.0f / TT);
    }
  } else {
    int c = bid - NI;
    for (int d = tid; d < DD; d += 256) {
      float acc = 0.f;
      const float* p = cap + (size_t)c * CL * DD + d;
      for (int t = 0; t < CL; ++t) acc += p[(size_t)t * DD];
      cap_avg[c * DD + d] = acc * (1.0f / CL);
    }
  }
}

// ------------------------------------------------- K2: h = tanh(avg@Wg+bg)*Wc
__global__ void k_hvec(const float* __restrict__ avg, const float* __restrict__ Wg,
                       const float* __restrict__ bg, const float* __restrict__ Wc,
                       float* __restrict__ h) {
  __shared__ float av[DD];
  int b = blockIdx.x >> 2;
  int dc = blockIdx.x & 3;
  int tid = threadIdx.x;
  for (int i = tid; i < DD; i += 256) av[i] = avg[b * DD + i];
  __syncthreads();
  int d = dc * 256 + tid;
  float acc = 0.f;
  for (int k = 0; k < DD; k += 4) {
    float4 a4 = *(const float4*)&av[k];
    acc += a4.x * Wg[(size_t)(k + 0) * DD + d];
    acc += a4.y * Wg[(size_t)(k + 1) * DD + d];
    acc += a4.z * Wg[(size_t)(k + 2) * DD + d];
    acc += a4.w * Wg[(size_t)(k + 3) * DD + d];
  }
  h[b * DD + d] = tanhf(acc + bg[d]) * Wc[d];
}

// ---------------- K3 (MFMA, merged img+cap): partial logits
__global__ void k_logits2(const unsigned short* __restrict__ Ai, const unsigned short* __restrict__ Wi,
                          const float* __restrict__ bli, const float* __restrict__ hi,
                          float* __restrict__ pi,
                          const unsigned short* __restrict__ Ac, const unsigned short* __restrict__ Wc2,
                          const float* __restrict__ blc, const float* __restrict__ hc,
                          float* __restrict__ pc) {
  int tid = threadIdx.x;
  int lane = tid & 63, w = tid >> 6;
  int lrow = lane & 15, lk = (lane >> 4) * 8, rsub = (lane >> 4) * 4;
  int bx = blockIdx.x;
  const unsigned short* Abf;
  const unsigned short* WT;
  const float* bl;
  const float* h;
  float* partial;
  int rb, rowsPerBatch;
  if (bx < 196) {
    Abf = Ai; WT = Wi; bl = bli; h = hi; partial = pi; rb = bx * 64; rowsPerBatch = TT;
  } else {
    Abf = Ac; WT = Wc2; bl = blc; h = hc; partial = pc; rb = (bx - 196) * 64; rowsPerBatch = CL;
  }
  int c0 = blockIdx.y * 64;
  const unsigned short* ap = Abf + (size_t)(rb + w * 16 + lrow) * DD;
  f32x4 acc[4] = {};
  for (int k0 = 0; k0 < DD; k0 += 32) {
    bfrag a = *(const bfrag*)(ap + k0 + lk);
#pragma unroll
    for (int i = 0; i < 4; ++i) {
      bfrag bb = *(const bfrag*)(WT + (size_t)(c0 + i * 16 + lrow) * DD + k0 + lk);
      acc[i] = MFMA(a, bb, acc[i]);
    }
  }
#pragma unroll
  for (int r = 0; r < 4; ++r) {
    int row = rb + w * 16 + rsub + r;
    int bb2 = row / rowsPerBatch;
    float s = 0.f;
#pragma unroll
    for (int i = 0; i < 4; ++i) {
      int col = c0 + i * 16 + lrow;
      s += tanhf(acc[i][r] + bl[col]) * h[bb2 * DD + col];
    }
    s += __shfl_xor(s, 1, 64);
    s += __shfl_xor(s, 2, 64);
    s += __shfl_xor(s, 4, 64);
    s += __shfl_xor(s, 8, 64);
    if (lrow == 0) partial[(size_t)row * 16 + blockIdx.y] = s;
  }
}

// -------- K4 (merged img+cap): finish global attention pooling
__global__ void k_finish2(const float* __restrict__ pi, const float* __restrict__ bci,
                          const float* __restrict__ Xi, long bsi, int Ri, float* __restrict__ oi,
                          const float* __restrict__ pc, const float* __restrict__ bcc,
                          const float* __restrict__ Xc, long bsc, int Rc, float* __restrict__ oc) {
  __shared__ float w[200];
  __shared__ float red[8];
  int bid = blockIdx.x, tid = threadIdx.x;
  const float* partial;
  const float* bc;
  const float* Xbase;
  long batchStride;
  int R, b;
  float* outG;
  if (bid < 64) {
    partial = pi; bc = bci; Xbase = Xi; batchStride = bsi; R = Ri; outG = oi; b = bid;
  } else {
    partial = pc; bc = bcc; Xbase = Xc; batchStride = bsc; R = Rc; outG = oc; b = bid - 64;
  }
  for (int t = tid; t < R; t += 256) {
    const float* pp = &partial[((size_t)b * R + t) * 16];
    float s = bc[0];
#pragma unroll
    for (int u = 0; u < 16; ++u) s += pp[u];
    w[t] = s;
  }
  __syncthreads();
  float m = -1e30f;
  for (int t = tid; t < R; t += 256) m = fmaxf(m, w[t]);
#pragma unroll
  for (int mm = 32; mm; mm >>= 1) m = fmaxf(m, __shfl_xor(m, mm, 64));
  if ((tid & 63) == 0) red[tid >> 6] = m;
  __syncthreads();
  m = fmaxf(fmaxf(red[0], red[1]), fmaxf(red[2], red[3]));
  __syncthreads();
  for (int t = tid; t < R; t += 256) w[t] = expf(w[t] - m);
  __syncthreads();
  const float* xb = Xbase + (size_t)b * batchStride;
  float acc[4];
  float ss = 0.f;
#pragma unroll
  for (int c4 = 0; c4 < 4; ++c4) {
    int d = tid + c4 * 256;
    float a = 0.f;
    for (int t = 0; t < R; ++t) a += w[t] * xb[(size_t)t * DD + d];
    acc[c4] = a;
    ss += a * a;
  }
  ss = warp_reduce_sum64(ss);
  if ((tid & 63) == 0) red[tid >> 6] = ss;
  __syncthreads();
  ss = red[0] + red[1] + red[2] + red[3];
  float rn = 1.0f / fmaxf(sqrtf(ss), EPSN);
#pragma unroll
  for (int c4 = 0; c4 < 4; ++c4) outG[(size_t)b * DD + tid + c4 * 256] = acc[c4] * rn;
}

// -------- K5: sim_glo
__global__ void k_simglo(const float* __restrict__ ig, const float* __restrict__ cg,
                         const float* __restrict__ W, const float* __restrict__ bgl,
                         float* __restrict__ simglo) {
  __shared__ float a_lds[32][20];
  __shared__ float b_lds[32][260];
  int tid = threadIdx.x;
  int p0 = blockIdx.x * 16;
  int ty = tid >> 6, tx = tid & 63;
  int s_rr = tid >> 3, s_kq = tid & 7;
  float acc[4][4] = {};
  for (int k0 = 0; k0 < DD; k0 += 32) {
    float d2[4] = {};
    if (tid < 128) {
      int p = p0 + s_rr;
      int b = p >> 6, c = p & 63;
      float4 giv = *(const float4*)&ig[b * DD + k0 + s_kq * 4];
      float4 cgv = *(const float4*)&cg[c * DD + k0 + s_kq * 4];
      float dx = giv.x - cgv.x, dy = giv.y - cgv.y, dz = giv.z - cgv.z, dw = giv.w - cgv.w;
      d2[0] = dx * dx; d2[1] = dy * dy; d2[2] = dz * dz; d2[3] = dw * dw;
    }
    float4 wv[8];
#pragma unroll
    for (int u = 0; u < 8; ++u)
      wv[u] = *(const float4*)&W[(size_t)(k0 + s_rr) * SS + s_kq * 32 + u * 4];
    __syncthreads();
    if (tid < 128) {
#pragma unroll
      for (int u = 0; u < 4; ++u) a_lds[s_kq * 4 + u][s_rr] = d2[u];
    }
#pragma unroll
    for (int u = 0; u < 8; ++u)
      *(float4*)&b_lds[s_rr][s_kq * 32 + u * 4] = wv[u];
    __syncthreads();
#pragma unroll
    for (int kk = 0; kk < 32; ++kk) {
      float4 a4 = *(const float4*)&a_lds[kk][ty * 4];
      float4 b4 = *(const float4*)&b_lds[kk][tx * 4];
      float av[4] = {a4.x, a4.y, a4.z, a4.w};
      float bv[4] = {b4.x, b4.y, b4.z, b4.w};
#pragma unroll
      for (int i = 0; i < 4; ++i)
#pragma unroll
        for (int j = 0; j < 4; ++j) acc[i][j] += av[i] * bv[j];
    }
  }
#pragma unroll
  for (int i = 0; i < 4; ++i) {
    float v[4];
    float ssq = 0.f;
#pragma unroll
    for (int j = 0; j < 4; ++j) {
      v[j] = acc[i][j] + bgl[tx * 4 + j];
      ssq += v[j] * v[j];
    }
    ssq = warp_reduce_sum64(ssq);
    float rn = 1.0f / fmaxf(sqrtf(ssq), EPSN);
    int p = p0 + ty * 4 + i;
    *(float4*)&simglo[(size_t)p * SS + tx * 4] =
        make_float4(v[0] * rn, v[1] * rn, v[2] * rn, v[3] * rn);
  }
}

// -------- K6: MT_bf16[t] = A_t @ B_t^T (256x256), bf16 out.
__global__ void k_mmatb(const float* __restrict__ Wa, const float* __restrict__ Wb,
                        unsigned short* __restrict__ M) {
  __shared__ float a_lds[32][68];
  __shared__ float b_lds[32][68];
  int tid = threadIdx.x;
  int t = blockIdx.x >> 4;
  int dt = (blockIdx.x >> 2) & 3, et = blockIdx.x & 3;
  int d0 = dt * 64, e0 = et * 64;
  const float* wq = Wa + (size_t)t * SS * SS;
  const float* wk = Wb + (size_t)t * SS * SS;
  int ty = tid >> 4, tx = tid & 15;
  int s_rr = tid >> 2, s_kq = tid & 3;
  float acc[4][4] = {};
  for (int j0 = 0; j0 < SS; j0 += 32) {
    float4 q0 = *(const float4*)&wq[(size_t)(d0 + s_rr) * SS + j0 + s_kq * 8];
    float4 q1 = *(const float4*)&wq[(size_t)(d0 + s_rr) * SS + j0 + s_kq * 8 + 4];
    float4 k0v = *(const float4*)&wk[(size_t)(e0 + s_rr) * SS + j0 + s_kq * 8];
    float4 k1v = *(const float4*)&wk[(size_t)(e0 + s_rr) * SS + j0 + s_kq * 8 + 4];
    __syncthreads();
    float qa[8] = {q0.x, q0.y, q0.z, q0.w, q1.x, q1.y, q1.z, q1.w};
    float ka[8] = {k0v.x, k0v.y, k0v.z, k0v.w, k1v.x, k1v.y, k1v.z, k1v.w};
#pragma unroll
    for (int u = 0; u < 8; ++u) {
      a_lds[s_kq * 8 + u][s_rr] = qa[u];
      b_lds[s_kq * 8 + u][s_rr] = ka[u];
    }
    __syncthreads();
#pragma unroll
    for (int kk = 0; kk < 32; ++kk) {
      float4 a4 = *(const float4*)&a_lds[kk][ty * 4];
      float4 b4 = *(const float4*)&b_lds[kk][tx * 4];
      float av[4] = {a4.x, a4.y, a4.z, a4.w};
      float bv[4] = {b4.x, b4.y, b4.z, b4.w};
#pragma unroll
      for (int i = 0; i < 4; ++i)
#pragma unroll
        for (int j = 0; j < 4; ++j) acc[i][j] += av[i] * bv[j];
    }
  }
#pragma unroll
  for (int i = 0; i < 4; ++i) {
    unsigned int lo = (unsigned int)f2b(acc[i][0]) | ((unsigned int)f2b(acc[i][1]) << 16);
    unsigned int hi = (unsigned int)f2b(acc[i][2]) | ((unsigned int)f2b(acc[i][3]) << 16);
    uint2 o = make_uint2(lo, hi);
    *(uint2*)(M + (size_t)t * SS * SS + (size_t)(d0 + ty * 4 + i) * SS + e0 + tx * 4) = o;
  }
}

// -------- K6b: wkbq[t] = Wk_t @ bq_t
__global__ void k_wkbq(const float* __restrict__ Wk, const float* __restrict__ bq,
                       float* __restrict__ out) {
  __shared__ float bv[SS];
  int t = blockIdx.x, tid = threadIdx.x;
  const float* wk = Wk + (size_t)t * SS * SS;
  bv[tid] = bq[t * SS + tid];
  __syncthreads();
  float acc = 0.f;
  for (int j = 0; j < SS; j += 4) {
    float4 wv = *(const float4*)&wk[(size_t)tid * SS + j];
    float4 b4 = *(const float4*)&bv[j];
    acc += wv.x * b4.x + wv.y * b4.y + wv.z * b4.z + wv.w * b4.w;
  }
  out[t * SS + tid] = acc;
}

// -------- fused img prep: row-major bf16 + transposed padded bf16 (one img read)
__global__ void k_imgprep(const float* __restrict__ img, unsigned short* __restrict__ row_bf,
                          unsigned short* __restrict__ tr_bf) {
  __shared__ float t[32][33];
  int b = blockIdx.z;
  int t0 = blockIdx.y * 32, d0 = blockIdx.x * 32;
  int tx = threadIdx.x & 31, ty = threadIdx.x >> 5;
#pragma unroll
  for (int u = 0; u < 4; ++u) {
    int tt = t0 + ty + u * 8;
    float v = (tt < TT) ? img[((size_t)b * NTOK + 1 + tt) * DD + d0 + tx] : 0.f;
    t[ty + u * 8][tx] = v;
    if (tt < TT) row_bf[((size_t)b * TT + tt) * DD + d0 + tx] = f2b(v);
  }
  __syncthreads();
#pragma unroll
  for (int u = 0; u < 4; ++u)
    tr_bf[((size_t)b * DD + d0 + ty + u * 8) * TP + t0 + tx] = f2b(t[tx][ty + u * 8]);
}

// -------- K6c (MFMA): gram_bf16[b] = imgTok_b @ imgTok_b^T in [208][224] zero-padded
__global__ void k_gram_mfma(const unsigned short* __restrict__ img_bf,
                            unsigned short* __restrict__ gram) {
  int tid = threadIdx.x;
  int lane = tid & 63, w = tid >> 6;
  int lrow = lane & 15, lk = (lane >> 4) * 8, rsub = (lane >> 4) * 4;
  int bimg = blockIdx.x;
  int rb = blockIdx.y * 64, cb = blockIdx.z * 64;
  const unsigned short* X = img_bf + (size_t)bimg * TT * DD;
  int ra = rb + w * 16 + lrow;
  if (ra > TT - 1) ra = TT - 1;
  f32x4 acc[4] = {};
  for (int k0 = 0; k0 < DD; k0 += 32) {
    bfrag a = *(const bfrag*)(X + (size_t)ra * DD + k0 + lk);
#pragma unroll
    for (int i = 0; i < 4; ++i) {
      int cc = cb + i * 16 + lrow;
      if (cc > TT - 1) cc = TT - 1;
      bfrag bb = *(const bfrag*)(X + (size_t)cc * DD + k0 + lk);
      acc[i] = MFMA(a, bb, acc[i]);
    }
  }
  unsigned short* Gp = gram + (size_t)bimg * 208 * TP;
#pragma unroll
  for (int i = 0; i < 4; ++i) {
    int cc = cb + i * 16 + lrow;
#pragma unroll
    for (int r = 0; r < 4; ++r) {
      int rr = rb + w * 16 + rsub + r;
      if (rr < 208 && cc < TP)
        Gp[(size_t)rr * TP + cc] = (rr < TT && cc < TT) ? f2b(acc[i][r]) : 0;
    }
  }
}

// -------- cast f32 -> bf16 (same layout)
__global__ void k_castb(const float* __restrict__ s, unsigned short* __restrict__ d, int n4) {
  int i = blockIdx.x * 256 + threadIdx.x;
  if (i < n4) {
    float4 v = *(const float4*)(s + (size_t)i * 4);
    uint2 o;
    o.x = (unsigned int)f2b(v.x) | ((unsigned int)f2b(v.y) << 16);
    o.y = (unsigned int)f2b(v.z) | ((unsigned int)f2b(v.w) << 16);
    *(uint2*)(d + (size_t)i * 4) = o;
  }
}

// -------- transpose-cast: src[R][C] f32 -> dst[C][R] bf16 (batched via z)
__global__ void k_tcast(const float* __restrict__ src, unsigned short* __restrict__ dst,
                        int R, int C, long sB, long dB) {
  __shared__ float t[32][33];
  const float* s = src + (size_t)blockIdx.z * sB;
  unsigned short* d = dst + (size_t)blockIdx.z * dB;
  int r0 = blockIdx.y * 32, c0 = blockIdx.x * 32;
  int tx = threadIdx.x & 31, ty = threadIdx.x >> 5;
#pragma unroll
  for (int u = 0; u < 4; ++u)
    t[ty + u * 8][tx] = s[(size_t)(r0 + ty + u * 8) * C + c0 + tx];
  __syncthreads();
#pragma unroll
  for (int u = 0; u < 4; ++u)
    d[(size_t)(c0 + ty + u * 8) * R + r0 + tx] = f2b(t[tx][ty + u * 8]);
}

// -------- K7: per-(img,cap) pair mega kernel (v9: 39.3KB LDS, bounds(256,3) -> no spill)
__global__ __launch_bounds__(256, 3) void k_pair(
    const float* __restrict__ b_loc, const float* __restrict__ simglo,
    const float* __restrict__ wkbq, const float* __restrict__ bg3,
    const float* __restrict__ W_eval, const float* __restrict__ b_eval,
    const unsigned short* __restrict__ cap_bf, const unsigned short* __restrict__ img_bf,
    const unsigned short* __restrict__ imgT_bf, const unsigned short* __restrict__ gram_bf,
    const unsigned short* __restrict__ wlocT_bf, const unsigned short* __restrict__ mt_bf,
    const unsigned short* __restrict__ wgT_bf, float* __restrict__ out) {
  extern __shared__ char smem[];

  int tid = threadIdx.x;
  int lane = tid & 63, w = tid >> 6;
  int lrow = lane & 15;        // MFMA row/col select
  int lk = (lane >> 4) * 8;    // MFMA k-offset
  int rsub = (lane >> 4) * 4;  // D-frag row base
  int p = blockIdx.x;
  int b = p >> 6, c = p & 63;
  const unsigned short* imgR = img_bf + (size_t)b * TT * DD;
  const unsigned short* capB = cap_bf + (size_t)c * CL * DD;
  char* attnT_b = smem + OFF_ATTNT;

  // ================ Phase A: S = leaky(imgTok.cap) MFMA; epilogue in registers
  {
    f32x4 acc[4][2] = {};
    for (int k0 = 0; k0 < DD; k0 += 32) {
      bfrag bq0 = *(const bfrag*)(capB + (size_t)lrow * DD + k0 + lk);
      bfrag bq1 = *(const bfrag*)(capB + (size_t)(16 + lrow) * DD + k0 + lk);
#pragma unroll
      for (int i = 0; i < 4; ++i) {
        int tt = w + 4 * i;
        if (tt < 13) {
          int t = tt * 16 + lrow;
          bfrag a = {0, 0, 0, 0, 0, 0, 0, 0};
          if (t < TT) a = *(const bfrag*)(imgR + (size_t)t * DD + k0 + lk);
          acc[i][0] = MFMA(a, bq0, acc[i][0]);
          acc[i][1] = MFMA(a, bq1, acc[i][1]);
        }
      }
    }
    // leaky + l2norm over q (16-lane butterfly within g-group) + running max over t
    float mx0 = -1e30f, mx1 = -1e30f;
#pragma unroll
    for (int i = 0; i < 4; ++i) {
      int tt = w + 4 * i;
      if (tt < 13) {
#pragma unroll
        for (int r = 0; r < 4; ++r) {
          int t = tt * 16 + rsub + r;
          float v0 = acc[i][0][r];
          v0 = v0 < 0.f ? 0.1f * v0 : v0;
          float v1 = acc[i][1][r];
          v1 = v1 < 0.f ? 0.1f * v1 : v1;
          float s2 = v0 * v0 + v1 * v1;
          s2 += __shfl_xor(s2, 1, 64);
          s2 += __shfl_xor(s2, 2, 64);
          s2 += __shfl_xor(s2, 4, 64);
          s2 += __shfl_xor(s2, 8, 64);
          float rn = 1.0f / fmaxf(sqrtf(s2), EPSN);
          v0 *= rn;
          v1 *= rn;
          acc[i][0][r] = v0;
          acc[i][1][r] = v1;
          if (t < TT) {
            mx0 = fmaxf(mx0, v0);
            mx1 = fmaxf(mx1, v1);
          }
        }
      }
    }
    mx0 = fmaxf(mx0, __shfl_xor(mx0, 16, 64));
    mx0 = fmaxf(mx0, __shfl_xor(mx0, 32, 64));
    mx1 = fmaxf(mx1, __shfl_xor(mx1, 16, 64));
    mx1 = fmaxf(mx1, __shfl_xor(mx1, 32, 64));
    float* wmax = (float*)(smem + OFF_WMAX);
    if ((lane >> 4) == 0) {
      wmax[w * 32 + lrow] = mx0;
      wmax[w * 32 + 16 + lrow] = mx1;
    }
    __syncthreads();
    mx0 = fmaxf(fmaxf(wmax[lrow], wmax[32 + lrow]), fmaxf(wmax[64 + lrow], wmax[96 + lrow]));
    mx1 = fmaxf(fmaxf(wmax[16 + lrow], wmax[48 + lrow]),
                fmaxf(wmax[80 + lrow], wmax[112 + lrow]));
    // exp (denominator dropped; exact since ctx l2-normalized) -> attnT bf16 [32][232]
#pragma unroll
    for (int i = 0; i < 4; ++i) {
      int tt = w + 4 * i;
#pragma unroll
      for (int r = 0; r < 4; ++r) {
        int t = tt * 16 + rsub + r;
        if (t < TP) {
          unsigned short e0 = 0, e1 = 0;
          if (t < TT) {
            e0 = f2b(expf(SMOOTHF * (acc[i][0][r] - mx0)));
            e1 = f2b(expf(SMOOTHF * (acc[i][1][r] - mx1)));
          }
          *(unsigned short*)(attnT_b + lrow * 464 + t * 2) = e0;
          *(unsigned short*)(attnT_b + (16 + lrow) * 464 + t * 2) = e1;
        }
      }
    }
  }
  __syncthreads();

  // ================ norm via Gram (MFMA): Y = G@E, norm2[q] = sum_t w[t][q]*Y[t][q]
  {
    float* qn = (float*)(smem + OFF_QN);
    float* nrmS = (float*)(smem + OFF_NRMS);
    const unsigned short* gb = gram_bf + (size_t)b * 208 * TP;
    float part0 = 0.f, part1 = 0.f;
#pragma unroll
    for (int i = 0; i < 4; ++i) {
      int tt = w + 4 * i;
      if (tt < 13) {
        f32x4 y0 = {0.f, 0.f, 0.f, 0.f}, y1 = {0.f, 0.f, 0.f, 0.f};
        for (int t0 = 0; t0 < TP; t0 += 32) {
          bfrag a = *(const bfrag*)(gb + (size_t)(tt * 16 + lrow) * TP + t0 + lk);
          bfrag b0 = *(const bfrag*)(attnT_b + lrow * 464 + (t0 + lk) * 2);
          bfrag b1 = *(const bfrag*)(attnT_b + (16 + lrow) * 464 + (t0 + lk) * 2);
          y0 = MFMA(a, b0, y0);
          y1 = MFMA(a, b1, y1);
        }
#pragma unroll
        for (int r = 0; r < 4; ++r) {
          int t = tt * 16 + rsub + r;
          if (t < TT) {
            part0 += y0[r] * b2f(*(const unsigned short*)(attnT_b + lrow * 464 + t * 2));
            part1 += y1[r] * b2f(*(const unsigned short*)(attnT_b + (16 + lrow) * 464 + t * 2));
          }
        }
      }
    }
    part0 += __shfl_xor(part0, 16, 64);
    part0 += __shfl_xor(part0, 32, 64);
    part1 += __shfl_xor(part1, 16, 64);
    part1 += __shfl_xor(part1, 32, 64);
    if ((lane >> 4) == 0) {
      qn[w * 32 + lrow] = part0;
      qn[w * 32 + 16 + lrow] = part1;
    }
    __syncthreads();
    if (tid < 32)
      nrmS[tid] = 1.0f / fmaxf(sqrtf(qn[tid] + qn[32 + tid] + qn[64 + tid] + qn[96 + tid]), EPSN);
    __syncthreads();
  }

  // ================ Phase W: ctx (MFMA) -> diff^2 -> @W_loc (MFMA)
  f32x4 accW[2][4] = {};
  {
    char* wtile_b = smem + OFF_WTILE;
    float* nrmS = (float*)(smem + OFF_NRMS);
    float nrm0 = nrmS[lrow], nrm1 = nrmS[16 + lrow];
    for (int d0 = 0; d0 < DD; d0 += 128) {
      f32x4 c2[2][2] = {};
      for (int t0 = 0; t0 < TP; t0 += 32) {
        bfrag b0 = *(const bfrag*)(attnT_b + lrow * 464 + (t0 + lk) * 2);
        bfrag b1 = *(const bfrag*)(attnT_b + (16 + lrow) * 464 + (t0 + lk) * 2);
#pragma unroll
        for (int i = 0; i < 2; ++i) {
          int dt = w + 4 * i;
          bfrag a = *(const bfrag*)(imgT_bf + ((size_t)b * DD + d0 + dt * 16 + lrow) * TP + t0 + lk);
          c2[i][0] = MFMA(a, b0, c2[i][0]);
          c2[i][1] = MFMA(a, b1, c2[i][1]);
        }
      }
      __syncthreads();  // prev W_loc readers of wtile done
#pragma unroll
      for (int i = 0; i < 2; ++i) {
        int dl = (w + 4 * i) * 16 + rsub;
#pragma unroll
        for (int qt = 0; qt < 2; ++qt) {
          int q = qt * 16 + lrow;
          uint2 cu = *(const uint2*)(capB + (size_t)q * DD + d0 + dl);
          float cf0 = b2f(cu.x & 0xffff), cf1 = b2f(cu.x >> 16);
          float cf2 = b2f(cu.y & 0xffff), cf3 = b2f(cu.y >> 16);
          float rn = qt ? nrm1 : nrm0;
          float v0 = c2[i][qt][0] * rn - cf0;
          float v1 = c2[i][qt][1] * rn - cf1;
          float v2 = c2[i][qt][2] * rn - cf2;
          float v3 = c2[i][qt][3] * rn - cf3;
          unsigned int lo = (unsigned int)f2b(v0 * v0) | ((unsigned int)f2b(v1 * v1) << 16);
          unsigned int hi = (unsigned int)f2b(v2 * v2) | ((unsigned int)f2b(v3 * v3) << 16);
          *(uint2*)(wtile_b + q * 272 + dl * 2) = make_uint2(lo, hi);
        }
      }
      __syncthreads();
      for (int kc = 0; kc < 4; ++kc) {
        bfrag a0 = *(const bfrag*)(wtile_b + lrow * 272 + (kc * 32 + lk) * 2);
        bfrag a1 = *(const bfrag*)(wtile_b + (16 + lrow) * 272 + (kc * 32 + lk) * 2);
#pragma unroll
        for (int sti = 0; sti < 4; ++sti) {
          int s = (w * 4 + sti) * 16 + lrow;
          bfrag bb = *(const bfrag*)(wlocT_bf + (size_t)s * DD + d0 + kc * 32 + lk);
          accW[0][sti] = MFMA(a0, bb, accW[0][sti]);
          accW[1][sti] = MFMA(a1, bb, accW[1][sti]);
        }
      }
    }
  }

  // ================ assembly: l2norm(sim_loc)+bias -> seA_bf16 rows 1..32; row 0 simglo
  {
    char* seA_b = smem + OFF_SEA;
    float* qn = (float*)(smem + OFF_QN);
    float* rnq = (float*)(smem + OFF_RNQ);
    __syncthreads();
    for (int i2 = tid; i2 < 6336; i2 += 256) ((unsigned int*)smem)[i2] = 0;  // zero seA
    __syncthreads();
    float blv[4];
#pragma unroll
    for (int sti = 0; sti < 4; ++sti) blv[sti] = b_loc[(w * 4 + sti) * 16 + lrow];
    float ss[2][4];
#pragma unroll
    for (int qt = 0; qt < 2; ++qt)
#pragma unroll
      for (int r = 0; r < 4; ++r) {
        float s2 = 0.f;
#pragma unroll
        for (int sti = 0; sti < 4; ++sti) {
          float v = accW[qt][sti][r] + blv[sti];
          s2 += v * v;
        }
        s2 += __shfl_xor(s2, 1, 64);
        s2 += __shfl_xor(s2, 2, 64);
        s2 += __shfl_xor(s2, 4, 64);
        s2 += __shfl_xor(s2, 8, 64);
        ss[qt][r] = s2;
      }
    if (lrow == 0) {
#pragma unroll
      for (int qt = 0; qt < 2; ++qt)
#pragma unroll
        for (int r = 0; r < 4; ++r)
          qn[w * 32 + qt * 16 + rsub + r] = ss[qt][r];
    }
    __syncthreads();
    if (tid < 32)
      rnq[tid] = 1.0f / fmaxf(sqrtf(qn[tid] + qn[32 + tid] + qn[64 + tid] + qn[96 + tid]), EPSN);
    __syncthreads();
#pragma unroll
    for (int qt = 0; qt < 2; ++qt)
#pragma unroll
      for (int r = 0; r < 4; ++r) {
        int q = qt * 16 + rsub + r;
        float rn = rnq[q];
#pragma unroll
        for (int sti = 0; sti < 4; ++sti) {
          int s = (w * 4 + sti) * 16 + lrow;
          float v = (accW[qt][sti][r] + blv[sti]) * rn;
          *(unsigned short*)(seA_b + (1 + q) * 528 + s * 2) = f2b(v);
        }
      }
    if (tid < 64) {
      float4 g4 = *(const float4*)&simglo[(size_t)p * SS + tid * 4];
      unsigned int lo = (unsigned int)f2b(g4.x) | ((unsigned int)f2b(g4.y) << 16);
      unsigned int hi = (unsigned int)f2b(g4.z) | ((unsigned int)f2b(g4.w) << 16);
      *(uint2*)(seA_b + tid * 8) = make_uint2(lo, hi);
    }
    __syncthreads();
  }

  // ================ SGR x3 (Eb 33 rows; pad-row reads alias R1 head -> discarded cols)
  {
    char* seA_b = smem + OFF_SEA;
    char* Gc_b = smem + OFF_R1;           // [48][144]B per e-chunk
    char* XT_b = smem + OFF_R1;           // [64][144]B per s-chunk
    float* Ef = (float*)(smem + OFF_R1);  // [33][34] f32 (after Gc dead)
    char* Eb = smem + OFF_EB;             // rows 0..32 x 144B physical
    float* wkq = (float*)(smem + OFF_WKQ);
    float* vbuf = (float*)(smem + OFF_VBUF);

    for (int step = 0; step < 3; ++step) {
      const unsigned short* mstep = mt_bf + (size_t)step * SS * SS;
      const unsigned short* wstep = wgT_bf + (size_t)step * SS * SS;
      wkq[tid] = wkbq[step * SS + tid];
      __syncthreads();
      // vbuf[m] = seA[m] . (Wk@bq)
      if (tid < 132) {
        int m = tid >> 2, qq = tid & 3;
        float a = 0.f;
        for (int e = qq * 64; e < qq * 64 + 64; e += 2) {
          unsigned int u = *(const unsigned int*)(seA_b + m * 528 + e * 2);
          a += b2f(u & 0xffff) * wkq[e] + b2f(u >> 16) * wkq[e + 1];
        }
        a += __shfl_xor(a, 1, 64);
        a += __shfl_xor(a, 2, 64);
        if (qq == 0) vbuf[m] = a;
      }
      // E = (seA@M) @ seA^T, e-chunked
      f32x4 aE[3] = {};
      for (int ec = 0; ec < 4; ++ec) {
        f32x4 aGc[3] = {};
        for (int kc = 0; kc < 8; ++kc) {
          int k = kc * 32 + lk;
          bfrag bb = *(const bfrag*)(mstep + (size_t)(ec * 64 + w * 16 + lrow) * SS + k);
#pragma unroll
          for (int mt = 0; mt < 3; ++mt) {
            bfrag af = *(const bfrag*)(seA_b + (mt * 16 + lrow) * 528 + k * 2);
            aGc[mt] = MFMA(af, bb, aGc[mt]);
          }
        }
        __syncthreads();  // prior chunk's Gc readers done
#pragma unroll
        for (int mt = 0; mt < 3; ++mt)
#pragma unroll
          for (int r = 0; r < 4; ++r)
            *(unsigned short*)(Gc_b + (mt * 16 + rsub + r) * 144 + (w * 16 + lrow) * 2) =
                f2b(aGc[mt][r]);
        __syncthreads();
#pragma unroll
        for (int kc = 0; kc < 2; ++kc) {
          int k = kc * 32 + lk;
#pragma unroll
          for (int ti = 0; ti < 3; ++ti) {
            int tile = w + ti * 4;
            if (tile < 9) {
              int mtE = tile / 3, ntE = tile - mtE * 3;
              bfrag ga = *(const bfrag*)(Gc_b + (mtE * 16 + lrow) * 144 + k * 2);
              bfrag sb = *(const bfrag*)(seA_b + (ntE * 16 + lrow) * 528 + (ec * 64 + k) * 2);
              aE[ti] = MFMA(ga, sb, aE[ti]);
            }
          }
        }
      }
      __syncthreads();  // all Gc reads done before Ef overlays it
#pragma unroll
      for (int ti = 0; ti < 3; ++ti) {
        int tile = w + ti * 4;
        if (tile < 9) {
          int mtE = tile / 3, ntE = tile - mtE * 3;
          int n0 = mtE * 16 + rsub, m = ntE * 16 + lrow;
#pragma unroll
          for (int r = 0; r < 4; ++r)
            if (n0 + r < NN && m < NN) Ef[(n0 + r) * 34 + m] = aE[ti][r] + vbuf[m];
        }
      }
      __syncthreads();
      // row softmax of E
      if (tid < NN) {
        float mx = -1e30f;
        for (int mm = 0; mm < NN; ++mm) mx = fmaxf(mx, Ef[tid * 34 + mm]);
        float sum = 0.f;
        for (int mm = 0; mm < NN; ++mm) {
          float e = expf(Ef[tid * 34 + mm] - mx);
          Ef[tid * 34 + mm] = e;
          sum += e;
        }
        float rs = 1.0f / sum;
        for (int mm = 0; mm < NN; ++mm) Ef[tid * 34 + mm] *= rs;
      }
      __syncthreads();
      // E_bf16 build: physical rows 0..32 only (reads of rows 33..47 hit R1 head,
      // producing garbage only in discarded output cols n>=33)
      for (int idx = tid; idx < 33 * 36; idx += 256) {
        int n = idx / 36, mp = (idx - n * 36) * 2;
        unsigned int lo = (mp < NN) ? (unsigned int)f2b(Ef[n * 34 + mp]) : 0u;
        unsigned int hi = (mp + 1 < NN) ? (unsigned int)f2b(Ef[n * 34 + mp + 1]) : 0u;
        *(unsigned int*)(Eb + n * 144 + mp * 2) = lo | (hi << 16);
      }
      __syncthreads();  // Eb ready; Ef dead -> XT may overlay
      // X = seA @ Wg per 64-col s-chunk; O = X^T@E^T per chunk, bias+relu+pack to regs
      unsigned int oPk[4][3][2];
#pragma unroll
      for (int sc = 0; sc < 4; ++sc) {
        f32x4 aX[3] = {};
        for (int kc = 0; kc < 8; ++kc) {
          int k = kc * 32 + lk;
          bfrag bb = *(const bfrag*)(wstep + (size_t)(sc * 64 + w * 16 + lrow) * SS + k);
#pragma unroll
          for (int mt = 0; mt < 3; ++mt) {
            bfrag af = *(const bfrag*)(seA_b + (mt * 16 + lrow) * 528 + k * 2);
            aX[mt] = MFMA(af, bb, aX[mt]);
          }
        }
        __syncthreads();  // prior chunk's XT readers done (sc=0: Eb barrier above)
#pragma unroll
        for (int mt = 0; mt < 3; ++mt) {
          unsigned int lo = (unsigned int)f2b(aX[mt][0]) | ((unsigned int)f2b(aX[mt][1]) << 16);
          unsigned int hi = (unsigned int)f2b(aX[mt][2]) | ((unsigned int)f2b(aX[mt][3]) << 16);
          *(uint2*)(XT_b + (w * 16 + lrow) * 144 + (mt * 16 + rsub) * 2) = make_uint2(lo, hi);
        }
        *(uint2*)(XT_b + (w * 16 + lrow) * 144 + (48 + rsub) * 2) = make_uint2(0, 0);
        __syncthreads();
        f32x4 aO[3] = {};
#pragma unroll
        for (int kc = 0; kc < 2; ++kc) {
          int k = kc * 32 + lk;
          bfrag xa = *(const bfrag*)(XT_b + (w * 16 + lrow) * 144 + k * 2);
#pragma unroll
          for (int nt = 0; nt < 3; ++nt) {
            bfrag eb = *(const bfrag*)(Eb + (nt * 16 + lrow) * 144 + k * 2);
            aO[nt] = MFMA(xa, eb, aO[nt]);
          }
        }
        float bga[4];
#pragma unroll
        for (int r = 0; r < 4; ++r) bga[r] = bg3[step * SS + sc * 64 + w * 16 + rsub + r];
#pragma unroll
        for (int nt = 0; nt < 3; ++nt) {
          float v0 = fmaxf(aO[nt][0] + bga[0], 0.f);
          float v1 = fmaxf(aO[nt][1] + bga[1], 0.f);
          float v2 = fmaxf(aO[nt][2] + bga[2], 0.f);
          float v3 = fmaxf(aO[nt][3] + bga[3], 0.f);
          oPk[sc][nt][0] = (unsigned int)f2b(v0) | ((unsigned int)f2b(v1) << 16);
          oPk[sc][nt][1] = (unsigned int)f2b(v2) | ((unsigned int)f2b(v3) << 16);
        }
      }
      // seA = relu(O + bg): all sc chunks' X reads of seA completed (barriers above)
#pragma unroll
      for (int sc = 0; sc < 4; ++sc)
#pragma unroll
        for (int nt = 0; nt < 3; ++nt) {
          int n = nt * 16 + lrow;
          if (n < NN)
            *(uint2*)(seA_b + n * 528 + (sc * 64 + w * 16 + rsub) * 2) =
                make_uint2(oPk[sc][nt][0], oPk[sc][nt][1]);
        }
      __syncthreads();
    }
  }

  // ================ eval: sigmoid(seA[0] @ W_eval + b_eval)
  if (tid < 64) {
    const char* seA_b = smem + OFF_SEA;
    uint2 u = *(const uint2*)(seA_b + tid * 8);
    float4 w4 = *(const float4*)&W_eval[tid * 4];
    float s = b2f(u.x & 0xffff) * w4.x + b2f(u.x >> 16) * w4.y +
              b2f(u.y & 0xffff) * w4.z + b2f(u.y >> 16) * w4.w;
    s = warp_reduce_sum64(s);
    if (tid == 0) out[b * 64 + c] = 1.0f / (1.0f + expf(-(s + b_eval[0])));
  }
}

extern "C" void kernel_launch(void* const* d_in, const int* in_sizes, int n_in,
                              void* d_out, int out_size, void* d_ws, size_t ws_size,
                              hipStream_t stream) {
  (void)in_sizes; (void)n_in; (void)out_size; (void)ws_size;
  const float* img = (const float*)d_in[0];
  const float* cap = (const float*)d_in[1];
  const float* vG_Wl = (const float*)d_in[3];
  const float* vG_bl = (const float*)d_in[4];
  const float* vG_Wg = (const float*)d_in[5];
  const float* vG_bg = (const float*)d_in[6];
  const float* vG_Wc = (const float*)d_in[7];
  const float* vG_bc = (const float*)d_in[8];
  const float* tG_Wl = (const float*)d_in[9];
  const float* tG_bl = (const float*)d_in[10];
  const float* tG_Wg = (const float*)d_in[11];
  const float* tG_bg = (const float*)d_in[12];
  const float* tG_Wc = (const float*)d_in[13];
  const float* tG_bc = (const float*)d_in[14];
  const float* W_loc = (const float*)d_in[15];
  const float* b_loc = (const float*)d_in[16];
  const float* W_glo = (const float*)d_in[17];
  const float* b_glo = (const float*)d_in[18];
  const float* W_eval = (const float*)d_in[19];
  const float* b_eval = (const float*)d_in[20];
  const float* sgr_Wq = (const float*)d_in[21];
  const float* sgr_bq = (const float*)d_in[22];
  const float* sgr_Wk = (const float*)d_in[23];
  const float* sgr_Wg = (const float*)d_in[25];
  const float* sgr_bg = (const float*)d_in[26];
  float* out = (float*)d_out;
  float* ws = (float*)d_ws;
  float* img_avg = ws;
  float* cap_avg = ws + 65536;
  float* h_img = ws + 131072;
  float* h_cap = ws + 196608;
  float* part_img = ws + 262144;
  float* part_cap = ws + 462848;
  float* img_glob = ws + 495616;
  float* cap_glob = ws + 561152;
  float* simglo = ws + 626688;
  float* wkbqv = ws + 1675264;
  // bf16 region (u16 units) starts at float offset 1676032 (16B aligned)
  unsigned short* ub = (unsigned short*)(ws + 1676032);
  unsigned short* mt_bf = ub;                   // 196608
  unsigned short* wgT_bf = ub + 196608;         // 196608 -> 393216
  unsigned short* wlocT_bf = ub + 393216;       // 262144 -> 655360
  unsigned short* cap_bf = ub + 655360;         // 2097152 -> 2752512
  unsigned short* gram_bf = ub + 2752512;       // 2981888 -> 5734400
  unsigned short* imgT_bf = ub + 5734400;       // 14680064 -> 20414464
  unsigned short* img_bf = ub + 20414464;       // 12845056 -> 33259520
  unsigned short* wlT_v = ub + 33259520;        // 1048576 -> 34308096
  unsigned short* wlT_t = ub + 34308096;        // 1048576 -> 35356672

  k_avg<<<128, 256, 0, stream>>>(img, cap, img_avg, cap_avg);
  k_hvec<<<256, 256, 0, stream>>>(img_avg, vG_Wg, vG_bg, vG_Wc, h_img);
  k_hvec<<<256, 256, 0, stream>>>(cap_avg, tG_Wg, tG_bg, tG_Wc, h_cap);
  k_imgprep<<<dim3(32, 7, 64), 256, 0, stream>>>(img, img_bf, imgT_bf);
  k_castb<<<2048, 256, 0, stream>>>(cap, cap_bf, 524288);
  k_tcast<<<dim3(32, 32, 1), 256, 0, stream>>>(vG_Wl, wlT_v, 1024, 1024, 0, 0);
  k_tcast<<<dim3(32, 32, 1), 256, 0, stream>>>(tG_Wl, wlT_t, 1024, 1024, 0, 0);
  k_logits2<<<dim3(228, 16), 256, 0, stream>>>(img_bf, wlT_v, vG_bl, h_img, part_img,
                                               cap_bf, wlT_t, tG_bl, h_cap, part_cap);
  k_finish2<<<128, 256, 0, stream>>>(part_img, vG_bc, img + DD, (long)NTOK * DD, TT, img_glob,
                                     part_cap, tG_bc, cap, (long)CL * DD, CL, cap_glob);
  k_simglo<<<256, 256, 0, stream>>>(img_glob, cap_glob, W_glo, b_glo, simglo);
  k_mmatb<<<48, 256, 0, stream>>>(sgr_Wk, sgr_Wq, mt_bf);  // MT = Wk@Wq^T = (Wq@Wk^T)^T
  k_wkbq<<<3, 256, 0, stream>>>(sgr_Wk, sgr_bq, wkbqv);
  k_gram_mfma<<<dim3(64, 4, 4), 256, 0, stream>>>(img_bf, gram_bf);
  k_tcast<<<dim3(8, 8, 3), 256, 0, stream>>>(sgr_Wg, wgT_bf, 256, 256, 65536, 65536);
  k_tcast<<<dim3(8, 32, 1), 256, 0, stream>>>(W_loc, wlocT_bf, 1024, 256, 0, 0);
  hipFuncSetAttribute((const void*)k_pair, hipFuncAttributeMaxDynamicSharedMemorySize,
                      SMEM_BYTES);
  k_pair<<<4096, 256, SMEM_BYTES, stream>>>(b_loc, simglo, wkbqv, sgr_bg, W_eval, b_eval,
                                            cap_bf, img_bf, imgT_bf, gram_bf, wlocT_bf,
                                            mt_bf, wgT_bf, out);
}

// Round 10
// 1814.770 us; speedup vs baseline: 1.0672x; 1.0672x over previous
//
#include <hip/hip_runtime.h>
#include <hip/hip_bf16.h>
#include <math.h>

#define NI 64
#define NC 64
#define NTOK 197
#define TT 196
#define CL 32
#define DD 1024
#define SS 256
#define NN 33
#define EPSN 1e-12f
#define SMOOTHF 9.0f
#define TP 224   // padded token dim for MFMA K

typedef __attribute__((ext_vector_type(8))) short bfrag;
typedef __attribute__((ext_vector_type(4))) float f32x4;
#define MFMA(a, b, c) __builtin_amdgcn_mfma_f32_16x16x32_bf16((a), (b), (c), 0, 0, 0)

// LDS layout (byte offsets) — phase A/W region (dead before SGR)
#define OFF_ATTNT  0        // [32][232] u16 = 14848
#define OFF_WTILE  14848    // [32][136] u16 = 8704 -> 23552
#define OFF_WMAX   23552    // [4][32] f32 = 512 -> 24064
#define OFF_NRMS   24064    // [32] f32 -> 24192
#define OFF_QN     24192    // [128] f32 -> 24704
#define OFF_RNQ    24704    // [32] f32 -> 24832
// SGR overlays
#define OFF_SEA    0        // [33][264] u16 = 17424 (MFMA reads "rows" to 47 alias EB/R1 ->
                            //  garbage feeds only discarded outputs n,m >= 33)
#define OFF_EB     17424    // [33][72] u16 = 4752 -> 22176 (reads of rows 33..47 alias R1 head)
#define OFF_R1     22176    // Gc 48*144=6912 / XT 64*144=9216 / Ef 33*34*4=4488 -> 31392
#define OFF_WKQ    29088    // [256] f32 -> 30112 (R1 tail after Gc; dead before XT writes)
#define OFF_VBUF   30112    // [36] f32 -> 30256 (ditto)
#define SMEM_BYTES 31392

__device__ __forceinline__ float warp_reduce_sum64(float v) {
#pragma unroll
  for (int m = 32; m > 0; m >>= 1) v += __shfl_xor(v, m, 64);
  return v;
}
__device__ __forceinline__ unsigned short f2b(float f) {
  __hip_bfloat16 h = __float2bfloat16(f);
  return *reinterpret_cast<unsigned short*>(&h);
}
__device__ __forceinline__ float b2f(unsigned short u) {
  union { unsigned int i; float f; } v;
  v.i = ((unsigned int)u) << 16;
  return v.f;
}

// ---------------------------------------------------------------- K1: means
__global__ void k_avg(const float* __restrict__ img, const float* __restrict__ cap,
                      float* __restrict__ img_avg, float* __restrict__ cap_avg) {
  int bid = blockIdx.x;
  int tid = threadIdx.x;
  if (bid < NI) {
    int b = bid;
    for (int d = tid; d < DD; d += 256) {
      float acc = 0.f;
      const float* p = img + ((size_t)b * NTOK + 1) * DD + d;
      for (int t = 0; t < TT; ++t) acc += p[(size_t)t * DD];
      img_avg[b * DD + d] = acc * (1.0f / TT);
    }
  } else {
    int c = bid - NI;
    for (int d = tid; d < DD; d += 256) {
      float acc = 0.f;
      const float* p = cap + (size_t)c * CL * DD + d;
      for (int t = 0; t < CL; ++t) acc += p[(size_t)t * DD];
      cap_avg[c * DD + d] = acc * (1.0f / CL);
    }
  }
}

// ------------------------------------------------- K2: h = tanh(avg@Wg+bg)*Wc
__global__ void k_hvec(const float* __restrict__ avg, const float* __restrict__ Wg,
                       const float* __restrict__ bg, const float* __restrict__ Wc,
                       float* __restrict__ h) {
  __shared__ float av[DD];
  int b = blockIdx.x >> 2;
  int dc = blockIdx.x & 3;
  int tid = threadIdx.x;
  for (int i = tid; i < DD; i += 256) av[i] = avg[b * DD + i];
  __syncthreads();
  int d = dc * 256 + tid;
  float acc = 0.f;
  for (int k = 0; k < DD; k += 4) {
    float4 a4 = *(const float4*)&av[k];
    acc += a4.x * Wg[(size_t)(k + 0) * DD + d];
    acc += a4.y * Wg[(size_t)(k + 1) * DD + d];
    acc += a4.z * Wg[(size_t)(k + 2) * DD + d];
    acc += a4.w * Wg[(size_t)(k + 3) * DD + d];
  }
  h[b * DD + d] = tanhf(acc + bg[d]) * Wc[d];
}

// ---------------- K3 (MFMA, merged img+cap): partial logits
__global__ void k_logits2(const unsigned short* __restrict__ Ai, const unsigned short* __restrict__ Wi,
                          const float* __restrict__ bli, const float* __restrict__ hi,
                          float* __restrict__ pi,
                          const unsigned short* __restrict__ Ac, const unsigned short* __restrict__ Wc2,
                          const float* __restrict__ blc, const float* __restrict__ hc,
                          float* __restrict__ pc) {
  int tid = threadIdx.x;
  int lane = tid & 63, w = tid >> 6;
  int lrow = lane & 15, lk = (lane >> 4) * 8, rsub = (lane >> 4) * 4;
  int bx = blockIdx.x;
  const unsigned short* Abf;
  const unsigned short* WT;
  const float* bl;
  const float* h;
  float* partial;
  int rb, rowsPerBatch;
  if (bx < 196) {
    Abf = Ai; WT = Wi; bl = bli; h = hi; partial = pi; rb = bx * 64; rowsPerBatch = TT;
  } else {
    Abf = Ac; WT = Wc2; bl = blc; h = hc; partial = pc; rb = (bx - 196) * 64; rowsPerBatch = CL;
  }
  int c0 = blockIdx.y * 64;
  const unsigned short* ap = Abf + (size_t)(rb + w * 16 + lrow) * DD;
  f32x4 acc[4] = {};
  for (int k0 = 0; k0 < DD; k0 += 32) {
    bfrag a = *(const bfrag*)(ap + k0 + lk);
#pragma unroll
    for (int i = 0; i < 4; ++i) {
      bfrag bb = *(const bfrag*)(WT + (size_t)(c0 + i * 16 + lrow) * DD + k0 + lk);
      acc[i] = MFMA(a, bb, acc[i]);
    }
  }
#pragma unroll
  for (int r = 0; r < 4; ++r) {
    int row = rb + w * 16 + rsub + r;
    int bb2 = row / rowsPerBatch;
    float s = 0.f;
#pragma unroll
    for (int i = 0; i < 4; ++i) {
      int col = c0 + i * 16 + lrow;
      s += tanhf(acc[i][r] + bl[col]) * h[bb2 * DD + col];
    }
    s += __shfl_xor(s, 1, 64);
    s += __shfl_xor(s, 2, 64);
    s += __shfl_xor(s, 4, 64);
    s += __shfl_xor(s, 8, 64);
    if (lrow == 0) partial[(size_t)row * 16 + blockIdx.y] = s;
  }
}

// -------- K4 (merged img+cap): finish global attention pooling
__global__ void k_finish2(const float* __restrict__ pi, const float* __restrict__ bci,
                          const float* __restrict__ Xi, long bsi, int Ri, float* __restrict__ oi,
                          const float* __restrict__ pc, const float* __restrict__ bcc,
                          const float* __restrict__ Xc, long bsc, int Rc, float* __restrict__ oc) {
  __shared__ float w[200];
  __shared__ float red[8];
  int bid = blockIdx.x, tid = threadIdx.x;
  const float* partial;
  const float* bc;
  const float* Xbase;
  long batchStride;
  int R, b;
  float* outG;
  if (bid < 64) {
    partial = pi; bc = bci; Xbase = Xi; batchStride = bsi; R = Ri; outG = oi; b = bid;
  } else {
    partial = pc; bc = bcc; Xbase = Xc; batchStride = bsc; R = Rc; outG = oc; b = bid - 64;
  }
  for (int t = tid; t < R; t += 256) {
    const float* pp = &partial[((size_t)b * R + t) * 16];
    float s = bc[0];
#pragma unroll
    for (int u = 0; u < 16; ++u) s += pp[u];
    w[t] = s;
  }
  __syncthreads();
  float m = -1e30f;
  for (int t = tid; t < R; t += 256) m = fmaxf(m, w[t]);
#pragma unroll
  for (int mm = 32; mm; mm >>= 1) m = fmaxf(m, __shfl_xor(m, mm, 64));
  if ((tid & 63) == 0) red[tid >> 6] = m;
  __syncthreads();
  m = fmaxf(fmaxf(red[0], red[1]), fmaxf(red[2], red[3]));
  __syncthreads();
  for (int t = tid; t < R; t += 256) w[t] = expf(w[t] - m);
  __syncthreads();
  const float* xb = Xbase + (size_t)b * batchStride;
  float acc[4];
  float ss = 0.f;
#pragma unroll
  for (int c4 = 0; c4 < 4; ++c4) {
    int d = tid + c4 * 256;
    float a = 0.f;
    for (int t = 0; t < R; ++t) a += w[t] * xb[(size_t)t * DD + d];
    acc[c4] = a;
    ss += a * a;
  }
  ss = warp_reduce_sum64(ss);
  if ((tid & 63) == 0) red[tid >> 6] = ss;
  __syncthreads();
  ss = red[0] + red[1] + red[2] + red[3];
  float rn = 1.0f / fmaxf(sqrtf(ss), EPSN);
#pragma unroll
  for (int c4 = 0; c4 < 4; ++c4) outG[(size_t)b * DD + tid + c4 * 256] = acc[c4] * rn;
}

// -------- K5: sim_glo
__global__ void k_simglo(const float* __restrict__ ig, const float* __restrict__ cg,
                         const float* __restrict__ W, const float* __restrict__ bgl,
                         float* __restrict__ simglo) {
  __shared__ float a_lds[32][20];
  __shared__ float b_lds[32][260];
  int tid = threadIdx.x;
  int p0 = blockIdx.x * 16;
  int ty = tid >> 6, tx = tid & 63;
  int s_rr = tid >> 3, s_kq = tid & 7;
  float acc[4][4] = {};
  for (int k0 = 0; k0 < DD; k0 += 32) {
    float d2[4] = {};
    if (tid < 128) {
      int p = p0 + s_rr;
      int b = p >> 6, c = p & 63;
      float4 giv = *(const float4*)&ig[b * DD + k0 + s_kq * 4];
      float4 cgv = *(const float4*)&cg[c * DD + k0 + s_kq * 4];
      float dx = giv.x - cgv.x, dy = giv.y - cgv.y, dz = giv.z - cgv.z, dw = giv.w - cgv.w;
      d2[0] = dx * dx; d2[1] = dy * dy; d2[2] = dz * dz; d2[3] = dw * dw;
    }
    float4 wv[8];
#pragma unroll
    for (int u = 0; u < 8; ++u)
      wv[u] = *(const float4*)&W[(size_t)(k0 + s_rr) * SS + s_kq * 32 + u * 4];
    __syncthreads();
    if (tid < 128) {
#pragma unroll
      for (int u = 0; u < 4; ++u) a_lds[s_kq * 4 + u][s_rr] = d2[u];
    }
#pragma unroll
    for (int u = 0; u < 8; ++u)
      *(float4*)&b_lds[s_rr][s_kq * 32 + u * 4] = wv[u];
    __syncthreads();
#pragma unroll
    for (int kk = 0; kk < 32; ++kk) {
      float4 a4 = *(const float4*)&a_lds[kk][ty * 4];
      float4 b4 = *(const float4*)&b_lds[kk][tx * 4];
      float av[4] = {a4.x, a4.y, a4.z, a4.w};
      float bv[4] = {b4.x, b4.y, b4.z, b4.w};
#pragma unroll
      for (int i = 0; i < 4; ++i)
#pragma unroll
        for (int j = 0; j < 4; ++j) acc[i][j] += av[i] * bv[j];
    }
  }
#pragma unroll
  for (int i = 0; i < 4; ++i) {
    float v[4];
    float ssq = 0.f;
#pragma unroll
    for (int j = 0; j < 4; ++j) {
      v[j] = acc[i][j] + bgl[tx * 4 + j];
      ssq += v[j] * v[j];
    }
    ssq = warp_reduce_sum64(ssq);
    float rn = 1.0f / fmaxf(sqrtf(ssq), EPSN);
    int p = p0 + ty * 4 + i;
    *(float4*)&simglo[(size_t)p * SS + tx * 4] =
        make_float4(v[0] * rn, v[1] * rn, v[2] * rn, v[3] * rn);
  }
}

// -------- K6: MT_bf16[t] = A_t @ B_t^T (256x256), bf16 out.
__global__ void k_mmatb(const float* __restrict__ Wa, const float* __restrict__ Wb,
                        unsigned short* __restrict__ M) {
  __shared__ float a_lds[32][68];
  __shared__ float b_lds[32][68];
  int tid = threadIdx.x;
  int t = blockIdx.x >> 4;
  int dt = (blockIdx.x >> 2) & 3, et = blockIdx.x & 3;
  int d0 = dt * 64, e0 = et * 64;
  const float* wq = Wa + (size_t)t * SS * SS;
  const float* wk = Wb + (size_t)t * SS * SS;
  int ty = tid >> 4, tx = tid & 15;
  int s_rr = tid >> 2, s_kq = tid & 3;
  float acc[4][4] = {};
  for (int j0 = 0; j0 < SS; j0 += 32) {
    float4 q0 = *(const float4*)&wq[(size_t)(d0 + s_rr) * SS + j0 + s_kq * 8];
    float4 q1 = *(const float4*)&wq[(size_t)(d0 + s_rr) * SS + j0 + s_kq * 8 + 4];
    float4 k0v = *(const float4*)&wk[(size_t)(e0 + s_rr) * SS + j0 + s_kq * 8];
    float4 k1v = *(const float4*)&wk[(size_t)(e0 + s_rr) * SS + j0 + s_kq * 8 + 4];
    __syncthreads();
    float qa[8] = {q0.x, q0.y, q0.z, q0.w, q1.x, q1.y, q1.z, q1.w};
    float ka[8] = {k0v.x, k0v.y, k0v.z, k0v.w, k1v.x, k1v.y, k1v.z, k1v.w};
#pragma unroll
    for (int u = 0; u < 8; ++u) {
      a_lds[s_kq * 8 + u][s_rr] = qa[u];
      b_lds[s_kq * 8 + u][s_rr] = ka[u];
    }
    __syncthreads();
#pragma unroll
    for (int kk = 0; kk < 32; ++kk) {
      float4 a4 = *(const float4*)&a_lds[kk][ty * 4];
      float4 b4 = *(const float4*)&b_lds[kk][tx * 4];
      float av[4] = {a4.x, a4.y, a4.z, a4.w};
      float bv[4] = {b4.x, b4.y, b4.z, b4.w};
#pragma unroll
      for (int i = 0; i < 4; ++i)
#pragma unroll
        for (int j = 0; j < 4; ++j) acc[i][j] += av[i] * bv[j];
    }
  }
#pragma unroll
  for (int i = 0; i < 4; ++i) {
    unsigned int lo = (unsigned int)f2b(acc[i][0]) | ((unsigned int)f2b(acc[i][1]) << 16);
    unsigned int hi = (unsigned int)f2b(acc[i][2]) | ((unsigned int)f2b(acc[i][3]) << 16);
    uint2 o = make_uint2(lo, hi);
    *(uint2*)(M + (size_t)t * SS * SS + (size_t)(d0 + ty * 4 + i) * SS + e0 + tx * 4) = o;
  }
}

// -------- K6b: wkbq[t] = Wk_t @ bq_t
__global__ void k_wkbq(const float* __restrict__ Wk, const float* __restrict__ bq,
                       float* __restrict__ out) {
  __shared__ float bv[SS];
  int t = blockIdx.x, tid = threadIdx.x;
  const float* wk = Wk + (size_t)t * SS * SS;
  bv[tid] = bq[t * SS + tid];
  __syncthreads();
  float acc = 0.f;
  for (int j = 0; j < SS; j += 4) {
    float4 wv = *(const float4*)&wk[(size_t)tid * SS + j];
    float4 b4 = *(const float4*)&bv[j];
    acc += wv.x * b4.x + wv.y * b4.y + wv.z * b4.z + wv.w * b4.w;
  }
  out[t * SS + tid] = acc;
}

// -------- fused img prep: row-major bf16 + transposed padded bf16 (one img read)
__global__ void k_imgprep(const float* __restrict__ img, unsigned short* __restrict__ row_bf,
                          unsigned short* __restrict__ tr_bf) {
  __shared__ float t[32][33];
  int b = blockIdx.z;
  int t0 = blockIdx.y * 32, d0 = blockIdx.x * 32;
  int tx = threadIdx.x & 31, ty = threadIdx.x >> 5;
#pragma unroll
  for (int u = 0; u < 4; ++u) {
    int tt = t0 + ty + u * 8;
    float v = (tt < TT) ? img[((size_t)b * NTOK + 1 + tt) * DD + d0 + tx] : 0.f;
    t[ty + u * 8][tx] = v;
    if (tt < TT) row_bf[((size_t)b * TT + tt) * DD + d0 + tx] = f2b(v);
  }
  __syncthreads();
#pragma unroll
  for (int u = 0; u < 4; ++u)
    tr_bf[((size_t)b * DD + d0 + ty + u * 8) * TP + t0 + tx] = f2b(t[tx][ty + u * 8]);
}

// -------- K6c (MFMA): gram_bf16[b] = imgTok_b @ imgTok_b^T in [208][224] zero-padded
__global__ void k_gram_mfma(const unsigned short* __restrict__ img_bf,
                            unsigned short* __restrict__ gram) {
  int tid = threadIdx.x;
  int lane = tid & 63, w = tid >> 6;
  int lrow = lane & 15, lk = (lane >> 4) * 8, rsub = (lane >> 4) * 4;
  int bimg = blockIdx.x;
  int rb = blockIdx.y * 64, cb = blockIdx.z * 64;
  const unsigned short* X = img_bf + (size_t)bimg * TT * DD;
  int ra = rb + w * 16 + lrow;
  if (ra > TT - 1) ra = TT - 1;
  f32x4 acc[4] = {};
  for (int k0 = 0; k0 < DD; k0 += 32) {
    bfrag a = *(const bfrag*)(X + (size_t)ra * DD + k0 + lk);
#pragma unroll
    for (int i = 0; i < 4; ++i) {
      int cc = cb + i * 16 + lrow;
      if (cc > TT - 1) cc = TT - 1;
      bfrag bb = *(const bfrag*)(X + (size_t)cc * DD + k0 + lk);
      acc[i] = MFMA(a, bb, acc[i]);
    }
  }
  unsigned short* Gp = gram + (size_t)bimg * 208 * TP;
#pragma unroll
  for (int i = 0; i < 4; ++i) {
    int cc = cb + i * 16 + lrow;
#pragma unroll
    for (int r = 0; r < 4; ++r) {
      int rr = rb + w * 16 + rsub + r;
      if (rr < 208 && cc < TP)
        Gp[(size_t)rr * TP + cc] = (rr < TT && cc < TT) ? f2b(acc[i][r]) : 0;
    }
  }
}

// -------- cast f32 -> bf16 (same layout)
__global__ void k_castb(const float* __restrict__ s, unsigned short* __restrict__ d, int n4) {
  int i = blockIdx.x * 256 + threadIdx.x;
  if (i < n4) {
    float4 v = *(const float4*)(s + (size_t)i * 4);
    uint2 o;
    o.x = (unsigned int)f2b(v.x) | ((unsigned int)f2b(v.y) << 16);
    o.y = (unsigned int)f2b(v.z) | ((unsigned int)f2b(v.w) << 16);
    *(uint2*)(d + (size_t)i * 4) = o;
  }
}

// -------- transpose-cast: src[R][C] f32 -> dst[C][R] bf16 (batched via z)
__global__ void k_tcast(const float* __restrict__ src, unsigned short* __restrict__ dst,
                        int R, int C, long sB, long dB) {
  __shared__ float t[32][33];
  const float* s = src + (size_t)blockIdx.z * sB;
  unsigned short* d = dst + (size_t)blockIdx.z * dB;
  int r0 = blockIdx.y * 32, c0 = blockIdx.x * 32;
  int tx = threadIdx.x & 31, ty = threadIdx.x >> 5;
#pragma unroll
  for (int u = 0; u < 4; ++u)
    t[ty + u * 8][tx] = s[(size_t)(r0 + ty + u * 8) * C + c0 + tx];
  __syncthreads();
#pragma unroll
  for (int u = 0; u < 4; ++u)
    d[(size_t)(c0 + ty + u * 8) * R + r0 + tx] = f2b(t[tx][ty + u * 8]);
}

// -------- K7: per-(img,cap) pair mega kernel (v10: 31.4KB LDS, AGPR diet, (256,4))
__global__ __launch_bounds__(256, 4) void k_pair(
    const float* __restrict__ b_loc, const float* __restrict__ simglo,
    const float* __restrict__ wkbq, const float* __restrict__ bg3,
    const float* __restrict__ W_eval, const float* __restrict__ b_eval,
    const unsigned short* __restrict__ cap_bf, const unsigned short* __restrict__ img_bf,
    const unsigned short* __restrict__ imgT_bf, const unsigned short* __restrict__ gram_bf,
    const unsigned short* __restrict__ wlocT_bf, const unsigned short* __restrict__ mt_bf,
    const unsigned short* __restrict__ wgT_bf, float* __restrict__ out) {
  extern __shared__ char smem[];

  int tid = threadIdx.x;
  int lane = tid & 63, w = tid >> 6;
  int lrow = lane & 15;        // MFMA row/col select
  int lk = (lane >> 4) * 8;    // MFMA k-offset
  int rsub = (lane >> 4) * 4;  // D-frag row base
  int p = blockIdx.x;
  int b = p >> 6, c = p & 63;
  const unsigned short* imgR = img_bf + (size_t)b * TT * DD;
  const unsigned short* capB = cap_bf + (size_t)c * CL * DD;
  char* attnT_b = smem + OFF_ATTNT;

  // ================ Phase A: S = leaky(imgTok.cap) MFMA; epilogue in registers
  {
    f32x4 acc[4][2] = {};
    for (int k0 = 0; k0 < DD; k0 += 32) {
      bfrag bq0 = *(const bfrag*)(capB + (size_t)lrow * DD + k0 + lk);
      bfrag bq1 = *(const bfrag*)(capB + (size_t)(16 + lrow) * DD + k0 + lk);
#pragma unroll
      for (int i = 0; i < 4; ++i) {
        int tt = w + 4 * i;
        if (tt < 13) {
          int t = tt * 16 + lrow;
          bfrag a = {0, 0, 0, 0, 0, 0, 0, 0};
          if (t < TT) a = *(const bfrag*)(imgR + (size_t)t * DD + k0 + lk);
          acc[i][0] = MFMA(a, bq0, acc[i][0]);
          acc[i][1] = MFMA(a, bq1, acc[i][1]);
        }
      }
    }
    // leaky + l2norm over q (16-lane butterfly within g-group) + running max over t
    float mx0 = -1e30f, mx1 = -1e30f;
#pragma unroll
    for (int i = 0; i < 4; ++i) {
      int tt = w + 4 * i;
      if (tt < 13) {
#pragma unroll
        for (int r = 0; r < 4; ++r) {
          int t = tt * 16 + rsub + r;
          float v0 = acc[i][0][r];
          v0 = v0 < 0.f ? 0.1f * v0 : v0;
          float v1 = acc[i][1][r];
          v1 = v1 < 0.f ? 0.1f * v1 : v1;
          float s2 = v0 * v0 + v1 * v1;
          s2 += __shfl_xor(s2, 1, 64);
          s2 += __shfl_xor(s2, 2, 64);
          s2 += __shfl_xor(s2, 4, 64);
          s2 += __shfl_xor(s2, 8, 64);
          float rn = 1.0f / fmaxf(sqrtf(s2), EPSN);
          v0 *= rn;
          v1 *= rn;
          acc[i][0][r] = v0;
          acc[i][1][r] = v1;
          if (t < TT) {
            mx0 = fmaxf(mx0, v0);
            mx1 = fmaxf(mx1, v1);
          }
        }
      }
    }
    mx0 = fmaxf(mx0, __shfl_xor(mx0, 16, 64));
    mx0 = fmaxf(mx0, __shfl_xor(mx0, 32, 64));
    mx1 = fmaxf(mx1, __shfl_xor(mx1, 16, 64));
    mx1 = fmaxf(mx1, __shfl_xor(mx1, 32, 64));
    float* wmax = (float*)(smem + OFF_WMAX);
    if ((lane >> 4) == 0) {
      wmax[w * 32 + lrow] = mx0;
      wmax[w * 32 + 16 + lrow] = mx1;
    }
    __syncthreads();
    mx0 = fmaxf(fmaxf(wmax[lrow], wmax[32 + lrow]), fmaxf(wmax[64 + lrow], wmax[96 + lrow]));
    mx1 = fmaxf(fmaxf(wmax[16 + lrow], wmax[48 + lrow]),
                fmaxf(wmax[80 + lrow], wmax[112 + lrow]));
    // exp (denominator dropped; exact since ctx l2-normalized) -> attnT bf16 [32][232]
#pragma unroll
    for (int i = 0; i < 4; ++i) {
      int tt = w + 4 * i;
#pragma unroll
      for (int r = 0; r < 4; ++r) {
        int t = tt * 16 + rsub + r;
        if (t < TP) {
          unsigned short e0 = 0, e1 = 0;
          if (t < TT) {
            e0 = f2b(expf(SMOOTHF * (acc[i][0][r] - mx0)));
            e1 = f2b(expf(SMOOTHF * (acc[i][1][r] - mx1)));
          }
          *(unsigned short*)(attnT_b + lrow * 464 + t * 2) = e0;
          *(unsigned short*)(attnT_b + (16 + lrow) * 464 + t * 2) = e1;
        }
      }
    }
  }
  __syncthreads();

  // ================ norm via Gram (MFMA): Y = G@E, norm2[q] = sum_t w[t][q]*Y[t][q]
  {
    float* qn = (float*)(smem + OFF_QN);
    float* nrmS = (float*)(smem + OFF_NRMS);
    const unsigned short* gb = gram_bf + (size_t)b * 208 * TP;
    float part0 = 0.f, part1 = 0.f;
#pragma unroll
    for (int i = 0; i < 4; ++i) {
      int tt = w + 4 * i;
      if (tt < 13) {
        f32x4 y0 = {0.f, 0.f, 0.f, 0.f}, y1 = {0.f, 0.f, 0.f, 0.f};
        for (int t0 = 0; t0 < TP; t0 += 32) {
          bfrag a = *(const bfrag*)(gb + (size_t)(tt * 16 + lrow) * TP + t0 + lk);
          bfrag b0 = *(const bfrag*)(attnT_b + lrow * 464 + (t0 + lk) * 2);
          bfrag b1 = *(const bfrag*)(attnT_b + (16 + lrow) * 464 + (t0 + lk) * 2);
          y0 = MFMA(a, b0, y0);
          y1 = MFMA(a, b1, y1);
        }
#pragma unroll
        for (int r = 0; r < 4; ++r) {
          int t = tt * 16 + rsub + r;
          if (t < TT) {
            part0 += y0[r] * b2f(*(const unsigned short*)(attnT_b + lrow * 464 + t * 2));
            part1 += y1[r] * b2f(*(const unsigned short*)(attnT_b + (16 + lrow) * 464 + t * 2));
          }
        }
      }
    }
    part0 += __shfl_xor(part0, 16, 64);
    part0 += __shfl_xor(part0, 32, 64);
    part1 += __shfl_xor(part1, 16, 64);
    part1 += __shfl_xor(part1, 32, 64);
    if ((lane >> 4) == 0) {
      qn[w * 32 + lrow] = part0;
      qn[w * 32 + 16 + lrow] = part1;
    }
    __syncthreads();
    if (tid < 32)
      nrmS[tid] = 1.0f / fmaxf(sqrtf(qn[tid] + qn[32 + tid] + qn[64 + tid] + qn[96 + tid]), EPSN);
    __syncthreads();
  }

  // ================ Phase W: ctx (MFMA, d-tile split for AGPR diet) -> diff^2 -> @W_loc
  f32x4 accW[2][4] = {};
  {
    char* wtile_b = smem + OFF_WTILE;
    float* nrmS = (float*)(smem + OFF_NRMS);
    float nrm0 = nrmS[lrow], nrm1 = nrmS[16 + lrow];
    for (int d0 = 0; d0 < DD; d0 += 128) {
#pragma unroll
      for (int i = 0; i < 2; ++i) {
        f32x4 c2[2] = {};
        int dt = w + 4 * i;
        const unsigned short* ib = imgT_bf + ((size_t)b * DD + d0 + dt * 16 + lrow) * TP;
        for (int t0 = 0; t0 < TP; t0 += 32) {
          bfrag b0 = *(const bfrag*)(attnT_b + lrow * 464 + (t0 + lk) * 2);
          bfrag b1 = *(const bfrag*)(attnT_b + (16 + lrow) * 464 + (t0 + lk) * 2);
          bfrag a = *(const bfrag*)(ib + t0 + lk);
          c2[0] = MFMA(a, b0, c2[0]);
          c2[1] = MFMA(a, b1, c2[1]);
        }
        if (i == 0) __syncthreads();  // prev W_loc readers of wtile done (hidden by i=0 compute)
        int dl = dt * 16 + rsub;
#pragma unroll
        for (int qt = 0; qt < 2; ++qt) {
          int q = qt * 16 + lrow;
          uint2 cu = *(const uint2*)(capB + (size_t)q * DD + d0 + dl);
          float cf0 = b2f(cu.x & 0xffff), cf1 = b2f(cu.x >> 16);
          float cf2 = b2f(cu.y & 0xffff), cf3 = b2f(cu.y >> 16);
          float rn = qt ? nrm1 : nrm0;
          float v0 = c2[qt][0] * rn - cf0;
          float v1 = c2[qt][1] * rn - cf1;
          float v2 = c2[qt][2] * rn - cf2;
          float v3 = c2[qt][3] * rn - cf3;
          unsigned int lo = (unsigned int)f2b(v0 * v0) | ((unsigned int)f2b(v1 * v1) << 16);
          unsigned int hi = (unsigned int)f2b(v2 * v2) | ((unsigned int)f2b(v3 * v3) << 16);
          *(uint2*)(wtile_b + q * 272 + dl * 2) = make_uint2(lo, hi);
        }
      }
      __syncthreads();
      for (int kc = 0; kc < 4; ++kc) {
        bfrag a0 = *(const bfrag*)(wtile_b + lrow * 272 + (kc * 32 + lk) * 2);
        bfrag a1 = *(const bfrag*)(wtile_b + (16 + lrow) * 272 + (kc * 32 + lk) * 2);
#pragma unroll
        for (int sti = 0; sti < 4; ++sti) {
          int s = (w * 4 + sti) * 16 + lrow;
          bfrag bb = *(const bfrag*)(wlocT_bf + (size_t)s * DD + d0 + kc * 32 + lk);
          accW[0][sti] = MFMA(a0, bb, accW[0][sti]);
          accW[1][sti] = MFMA(a1, bb, accW[1][sti]);
        }
      }
    }
  }

  // ================ assembly: l2norm(sim_loc)+bias -> seA_bf16 rows 1..32; row 0 simglo
  {
    char* seA_b = smem + OFF_SEA;
    float* qn = (float*)(smem + OFF_QN);
    float* rnq = (float*)(smem + OFF_RNQ);
    __syncthreads();  // phase W wtile/attnT reads done before seA overlays them
    float blv[4];
#pragma unroll
    for (int sti = 0; sti < 4; ++sti) blv[sti] = b_loc[(w * 4 + sti) * 16 + lrow];
    float ss[2][4];
#pragma unroll
    for (int qt = 0; qt < 2; ++qt)
#pragma unroll
      for (int r = 0; r < 4; ++r) {
        float s2 = 0.f;
#pragma unroll
        for (int sti = 0; sti < 4; ++sti) {
          float v = accW[qt][sti][r] + blv[sti];
          s2 += v * v;
        }
        s2 += __shfl_xor(s2, 1, 64);
        s2 += __shfl_xor(s2, 2, 64);
        s2 += __shfl_xor(s2, 4, 64);
        s2 += __shfl_xor(s2, 8, 64);
        ss[qt][r] = s2;
      }
    if (lrow == 0) {
#pragma unroll
      for (int qt = 0; qt < 2; ++qt)
#pragma unroll
        for (int r = 0; r < 4; ++r)
          qn[w * 32 + qt * 16 + rsub + r] = ss[qt][r];
    }
    __syncthreads();
    if (tid < 32)
      rnq[tid] = 1.0f / fmaxf(sqrtf(qn[tid] + qn[32 + tid] + qn[64 + tid] + qn[96 + tid]), EPSN);
    __syncthreads();
#pragma unroll
    for (int qt = 0; qt < 2; ++qt)
#pragma unroll
      for (int r = 0; r < 4; ++r) {
        int q = qt * 16 + rsub + r;
        float rn = rnq[q];
#pragma unroll
        for (int sti = 0; sti < 4; ++sti) {
          int s = (w * 4 + sti) * 16 + lrow;
          float v = (accW[qt][sti][r] + blv[sti]) * rn;
          *(unsigned short*)(seA_b + (1 + q) * 528 + s * 2) = f2b(v);
        }
      }
    if (tid < 64) {
      float4 g4 = *(const float4*)&simglo[(size_t)p * SS + tid * 4];
      unsigned int lo = (unsigned int)f2b(g4.x) | ((unsigned int)f2b(g4.y) << 16);
      unsigned int hi = (unsigned int)f2b(g4.z) | ((unsigned int)f2b(g4.w) << 16);
      *(uint2*)(seA_b + tid * 8) = make_uint2(lo, hi);
    }
    __syncthreads();
  }

  // ================ SGR x3 (33-row seA; aliased pad reads feed only discarded outputs)
  {
    char* seA_b = smem + OFF_SEA;
    char* Gc_b = smem + OFF_R1;           // [48][144]B per e-chunk
    char* XT_b = smem + OFF_R1;           // [64][144]B per s-chunk
    float* Ef = (float*)(smem + OFF_R1);  // [33][34] f32 (after Gc dead)
    char* Eb = smem + OFF_EB;             // rows 0..32 x 144B physical
    float* wkq = (float*)(smem + OFF_WKQ);
    float* vbuf = (float*)(smem + OFF_VBUF);

    for (int step = 0; step < 3; ++step) {
      const unsigned short* mstep = mt_bf + (size_t)step * SS * SS;
      const unsigned short* wstep = wgT_bf + (size_t)step * SS * SS;
      wkq[tid] = wkbq[step * SS + tid];
      __syncthreads();
      // vbuf[m] = seA[m] . (Wk@bq)
      if (tid < 132) {
        int m = tid >> 2, qq = tid & 3;
        float a = 0.f;
        for (int e = qq * 64; e < qq * 64 + 64; e += 2) {
          unsigned int u = *(const unsigned int*)(seA_b + m * 528 + e * 2);
          a += b2f(u & 0xffff) * wkq[e] + b2f(u >> 16) * wkq[e + 1];
        }
        a += __shfl_xor(a, 1, 64);
        a += __shfl_xor(a, 2, 64);
        if (qq == 0) vbuf[m] = a;
      }
      // E = (seA@M) @ seA^T, e-chunked
      f32x4 aE[3] = {};
      for (int ec = 0; ec < 4; ++ec) {
        f32x4 aGc[3] = {};
        for (int kc = 0; kc < 8; ++kc) {
          int k = kc * 32 + lk;
          bfrag bb = *(const bfrag*)(mstep + (size_t)(ec * 64 + w * 16 + lrow) * SS + k);
#pragma unroll
          for (int mt = 0; mt < 3; ++mt) {
            bfrag af = *(const bfrag*)(seA_b + (mt * 16 + lrow) * 528 + k * 2);
            aGc[mt] = MFMA(af, bb, aGc[mt]);
          }
        }
        __syncthreads();  // prior chunk's Gc readers done
#pragma unroll
        for (int mt = 0; mt < 3; ++mt)
#pragma unroll
          for (int r = 0; r < 4; ++r)
            *(unsigned short*)(Gc_b + (mt * 16 + rsub + r) * 144 + (w * 16 + lrow) * 2) =
                f2b(aGc[mt][r]);
        __syncthreads();
#pragma unroll
        for (int kc = 0; kc < 2; ++kc) {
          int k = kc * 32 + lk;
#pragma unroll
          for (int ti = 0; ti < 3; ++ti) {
            int tile = w + ti * 4;
            if (tile < 9) {
              int mtE = tile / 3, ntE = tile - mtE * 3;
              bfrag ga = *(const bfrag*)(Gc_b + (mtE * 16 + lrow) * 144 + k * 2);
              bfrag sb = *(const bfrag*)(seA_b + (ntE * 16 + lrow) * 528 + (ec * 64 + k) * 2);
              aE[ti] = MFMA(ga, sb, aE[ti]);
            }
          }
        }
      }
      __syncthreads();  // all Gc reads done before Ef overlays it
#pragma unroll
      for (int ti = 0; ti < 3; ++ti) {
        int tile = w + ti * 4;
        if (tile < 9) {
          int mtE = tile / 3, ntE = tile - mtE * 3;
          int n0 = mtE * 16 + rsub, m = ntE * 16 + lrow;
#pragma unroll
          for (int r = 0; r < 4; ++r)
            if (n0 + r < NN && m < NN) Ef[(n0 + r) * 34 + m] = aE[ti][r] + vbuf[m];
        }
      }
      __syncthreads();
      // row softmax of E
      if (tid < NN) {
        float mx = -1e30f;
        for (int mm = 0; mm < NN; ++mm) mx = fmaxf(mx, Ef[tid * 34 + mm]);
        float sum = 0.f;
        for (int mm = 0; mm < NN; ++mm) {
          float e = expf(Ef[tid * 34 + mm] - mx);
          Ef[tid * 34 + mm] = e;
          sum += e;
        }
        float rs = 1.0f / sum;
        for (int mm = 0; mm < NN; ++mm) Ef[tid * 34 + mm] *= rs;
      }
      __syncthreads();
      // E_bf16 build: physical rows 0..32; cols >= NN zeroed (kills XT garbage k-terms)
      for (int idx = tid; idx < 33 * 36; idx += 256) {
        int n = idx / 36, mp = (idx - n * 36) * 2;
        unsigned int lo = (mp < NN) ? (unsigned int)f2b(Ef[n * 34 + mp]) : 0u;
        unsigned int hi = (mp + 1 < NN) ? (unsigned int)f2b(Ef[n * 34 + mp + 1]) : 0u;
        *(unsigned int*)(Eb + n * 144 + mp * 2) = lo | (hi << 16);
      }
      __syncthreads();  // Eb ready; Ef dead -> XT may overlay
      // X = seA @ Wg per 64-col s-chunk; O = X^T@E^T per chunk, bias+relu+pack to regs
      unsigned int oPk[4][3][2];
#pragma unroll
      for (int sc = 0; sc < 4; ++sc) {
        f32x4 aX[3] = {};
        for (int kc = 0; kc < 8; ++kc) {
          int k = kc * 32 + lk;
          bfrag bb = *(const bfrag*)(wstep + (size_t)(sc * 64 + w * 16 + lrow) * SS + k);
#pragma unroll
          for (int mt = 0; mt < 3; ++mt) {
            bfrag af = *(const bfrag*)(seA_b + (mt * 16 + lrow) * 528 + k * 2);
            aX[mt] = MFMA(af, bb, aX[mt]);
          }
        }
        __syncthreads();  // prior chunk's XT readers done (sc=0: Eb barrier above)
#pragma unroll
        for (int mt = 0; mt < 3; ++mt) {
          unsigned int lo = (unsigned int)f2b(aX[mt][0]) | ((unsigned int)f2b(aX[mt][1]) << 16);
          unsigned int hi = (unsigned int)f2b(aX[mt][2]) | ((unsigned int)f2b(aX[mt][3]) << 16);
          *(uint2*)(XT_b + (w * 16 + lrow) * 144 + (mt * 16 + rsub) * 2) = make_uint2(lo, hi);
        }
        *(uint2*)(XT_b + (w * 16 + lrow) * 144 + (48 + rsub) * 2) = make_uint2(0, 0);
        __syncthreads();
        f32x4 aO[3] = {};
#pragma unroll
        for (int kc = 0; kc < 2; ++kc) {
          int k = kc * 32 + lk;
          bfrag xa = *(const bfrag*)(XT_b + (w * 16 + lrow) * 144 + k * 2);
#pragma unroll
          for (int nt = 0; nt < 3; ++nt) {
            bfrag eb = *(const bfrag*)(Eb + (nt * 16 + lrow) * 144 + k * 2);
            aO[nt] = MFMA(xa, eb, aO[nt]);
          }
        }
        float bga[4];
#pragma unroll
        for (int r = 0; r < 4; ++r) bga[r] = bg3[step * SS + sc * 64 + w * 16 + rsub + r];
#pragma unroll
        for (int nt = 0; nt < 3; ++nt) {
          float v0 = fmaxf(aO[nt][0] + bga[0], 0.f);
          float v1 = fmaxf(aO[nt][1] + bga[1], 0.f);
          float v2 = fmaxf(aO[nt][2] + bga[2], 0.f);
          float v3 = fmaxf(aO[nt][3] + bga[3], 0.f);
          oPk[sc][nt][0] = (unsigned int)f2b(v0) | ((unsigned int)f2b(v1) << 16);
          oPk[sc][nt][1] = (unsigned int)f2b(v2) | ((unsigned int)f2b(v3) << 16);
        }
      }
      // seA = relu(O + bg): all sc chunks' X reads of seA completed (barriers above)
#pragma unroll
      for (int sc = 0; sc < 4; ++sc)
#pragma unroll
        for (int nt = 0; nt < 3; ++nt) {
          int n = nt * 16 + lrow;
          if (n < NN)
            *(uint2*)(seA_b + n * 528 + (sc * 64 + w * 16 + rsub) * 2) =
                make_uint2(oPk[sc][nt][0], oPk[sc][nt][1]);
        }
      __syncthreads();
    }
  }

  // ================ eval: sigmoid(seA[0] @ W_eval + b_eval)
  if (tid < 64) {
    const char* seA_b = smem + OFF_SEA;
    uint2 u = *(const uint2*)(seA_b + tid * 8);
    float4 w4 = *(const float4*)&W_eval[tid * 4];
    float s = b2f(u.x & 0xffff) * w4.x + b2f(u.x >> 16) * w4.y +
              b2f(u.y & 0xffff) * w4.z + b2f(u.y >> 16) * w4.w;
    s = warp_reduce_sum64(s);
    if (tid == 0) out[b * 64 + c] = 1.0f / (1.0f + expf(-(s + b_eval[0])));
  }
}

extern "C" void kernel_launch(void* const* d_in, const int* in_sizes, int n_in,
                              void* d_out, int out_size, void* d_ws, size_t ws_size,
                              hipStream_t stream) {
  (void)in_sizes; (void)n_in; (void)out_size; (void)ws_size;
  const float* img = (const float*)d_in[0];
  const float* cap = (const float*)d_in[1];
  const float* vG_Wl = (const float*)d_in[3];
  const float* vG_bl = (const float*)d_in[4];
  const float* vG_Wg = (const float*)d_in[5];
  const float* vG_bg = (const float*)d_in[6];
  const float* vG_Wc = (const float*)d_in[7];
  const float* vG_bc = (const float*)d_in[8];
  const float* tG_Wl = (const float*)d_in[9];
  const float* tG_bl = (const float*)d_in[10];
  const float* tG_Wg = (const float*)d_in[11];
  const float* tG_bg = (const float*)d_in[12];
  const float* tG_Wc = (const float*)d_in[13];
  const float* tG_bc = (const float*)d_in[14];
  const float* W_loc = (const float*)d_in[15];
  const float* b_loc = (const float*)d_in[16];
  const float* W_glo = (const float*)d_in[17];
  const float* b_glo = (const float*)d_in[18];
  const float* W_eval = (const float*)d_in[19];
  const float* b_eval = (const float*)d_in[20];
  const float* sgr_Wq = (const float*)d_in[21];
  const float* sgr_bq = (const float*)d_in[22];
  const float* sgr_Wk = (const float*)d_in[23];
  const float* sgr_Wg = (const float*)d_in[25];
  const float* sgr_bg = (const float*)d_in[26];
  float* out = (float*)d_out;
  float* ws = (float*)d_ws;
  float* img_avg = ws;
  float* cap_avg = ws + 65536;
  float* h_img = ws + 131072;
  float* h_cap = ws + 196608;
  float* part_img = ws + 262144;
  float* part_cap = ws + 462848;
  float* img_glob = ws + 495616;
  float* cap_glob = ws + 561152;
  float* simglo = ws + 626688;
  float* wkbqv = ws + 1675264;
  // bf16 region (u16 units) starts at float offset 1676032 (16B aligned)
  unsigned short* ub = (unsigned short*)(ws + 1676032);
  unsigned short* mt_bf = ub;                   // 196608
  unsigned short* wgT_bf = ub + 196608;         // 196608 -> 393216
  unsigned short* wlocT_bf = ub + 393216;       // 262144 -> 655360
  unsigned short* cap_bf = ub + 655360;         // 2097152 -> 2752512
  unsigned short* gram_bf = ub + 2752512;       // 2981888 -> 5734400
  unsigned short* imgT_bf = ub + 5734400;       // 14680064 -> 20414464
  unsigned short* img_bf = ub + 20414464;       // 12845056 -> 33259520
  unsigned short* wlT_v = ub + 33259520;        // 1048576 -> 34308096
  unsigned short* wlT_t = ub + 34308096;        // 1048576 -> 35356672

  k_avg<<<128, 256, 0, stream>>>(img, cap, img_avg, cap_avg);
  k_hvec<<<256, 256, 0, stream>>>(img_avg, vG_Wg, vG_bg, vG_Wc, h_img);
  k_hvec<<<256, 256, 0, stream>>>(cap_avg, tG_Wg, tG_bg, tG_Wc, h_cap);
  k_imgprep<<<dim3(32, 7, 64), 256, 0, stream>>>(img, img_bf, imgT_bf);
  k_castb<<<2048, 256, 0, stream>>>(cap, cap_bf, 524288);
  k_tcast<<<dim3(32, 32, 1), 256, 0, stream>>>(vG_Wl, wlT_v, 1024, 1024, 0, 0);
  k_tcast<<<dim3(32, 32, 1), 256, 0, stream>>>(tG_Wl, wlT_t, 1024, 1024, 0, 0);
  k_logits2<<<dim3(228, 16), 256, 0, stream>>>(img_bf, wlT_v, vG_bl, h_img, part_img,
                                               cap_bf, wlT_t, tG_bl, h_cap, part_cap);
  k_finish2<<<128, 256, 0, stream>>>(part_img, vG_bc, img + DD, (long)NTOK * DD, TT, img_glob,
                                     part_cap, tG_bc, cap, (long)CL * DD, CL, cap_glob);
  k_simglo<<<256, 256, 0, stream>>>(img_glob, cap_glob, W_glo, b_glo, simglo);
  k_mmatb<<<48, 256, 0, stream>>>(sgr_Wk, sgr_Wq, mt_bf);  // MT = Wk@Wq^T = (Wq@Wk^T)^T
  k_wkbq<<<3, 256, 0, stream>>>(sgr_Wk, sgr_bq, wkbqv);
  k_gram_mfma<<<dim3(64, 4, 4), 256, 0, stream>>>(img_bf, gram_bf);
  k_tcast<<<dim3(8, 8, 3), 256, 0, stream>>>(sgr_Wg, wgT_bf, 256, 256, 65536, 65536);
  k_tcast<<<dim3(8, 32, 1), 256, 0, stream>>>(W_loc, wlocT_bf, 1024, 256, 0, 0);
  hipFuncSetAttribute((const void*)k_pair, hipFuncAttributeMaxDynamicSharedMemorySize,
                      SMEM_BYTES);
  k_pair<<<4096, 256, SMEM_BYTES, stream>>>(b_loc, simglo, wkbqv, sgr_bg, W_eval, b_eval,
                                            cap_bf, img_bf, imgT_bf, gram_bf, wlocT_bf,
                                            mt_bf, wgT_bf, out);
}

// Round 11
// 1717.278 us; speedup vs baseline: 1.1278x; 1.0568x over previous
//
#include <hip/hip_runtime.h>
#include <hip/hip_bf16.h>
#include <math.h>

#define NI 64
#define NC 64
#define NTOK 197
#define TT 196
#define CL 32
#define DD 1024
#define SS 256
#define NN 33
#define EPSN 1e-12f
#define SMOOTHF 9.0f
#define TP 224   // padded token dim for MFMA K

typedef __attribute__((ext_vector_type(8))) short bfrag;
typedef __attribute__((ext_vector_type(4))) float f32x4;
#define MFMA(a, b, c) __builtin_amdgcn_mfma_f32_16x16x32_bf16((a), (b), (c), 0, 0, 0)

// LDS layout (byte offsets) — phase A/W region (dead before SGR)
#define OFF_ATTNT  0        // [32][232] u16 = 14848
#define OFF_WTILE  14848    // [32][136] u16 = 8704 -> 23552
#define OFF_WMAX   23552    // [4][32] f32 = 512 -> 24064
#define OFF_NRMS   24064    // [32] f32 -> 24192
#define OFF_QN     24192    // [128] f32 -> 24704
#define OFF_RNQ    24704    // [32] f32 -> 24832
// SGR overlays
#define OFF_SEA    0        // [33][264] u16 = 17424 (MFMA reads "rows" to 47 alias EB/R1 ->
                            //  garbage feeds only discarded outputs n,m >= 33)
#define OFF_EB     17424    // [33][72] u16 = 4752 -> 22176 (reads of rows 33..47 alias R1 head)
#define OFF_R1     22176    // Gc 48*144=6912 / XT 64*144=9216 / Ef 33*34*4=4488 -> 31392
#define OFF_WKQ    29088    // [256] f32 -> 30112 (R1 tail after Gc; dead before XT writes)
#define OFF_VBUF   30112    // [36] f32 -> 30256 (ditto)
#define SMEM_BYTES 31392

__device__ __forceinline__ float warp_reduce_sum64(float v) {
#pragma unroll
  for (int m = 32; m > 0; m >>= 1) v += __shfl_xor(v, m, 64);
  return v;
}
__device__ __forceinline__ unsigned short f2b(float f) {
  __hip_bfloat16 h = __float2bfloat16(f);
  return *reinterpret_cast<unsigned short*>(&h);
}
__device__ __forceinline__ float b2f(unsigned short u) {
  union { unsigned int i; float f; } v;
  v.i = ((unsigned int)u) << 16;
  return v.f;
}

// ---------------------------------------------------------------- K1: means
__global__ void k_avg(const float* __restrict__ img, const float* __restrict__ cap,
                      float* __restrict__ img_avg, float* __restrict__ cap_avg) {
  int bid = blockIdx.x;
  int tid = threadIdx.x;
  if (bid < NI) {
    int b = bid;
    for (int d = tid; d < DD; d += 256) {
      float acc = 0.f;
      const float* p = img + ((size_t)b * NTOK + 1) * DD + d;
      for (int t = 0; t < TT; ++t) acc += p[(size_t)t * DD];
      img_avg[b * DD + d] = acc * (1.0f / TT);
    }
  } else {
    int c = bid - NI;
    for (int d = tid; d < DD; d += 256) {
      float acc = 0.f;
      const float* p = cap + (size_t)c * CL * DD + d;
      for (int t = 0; t < CL; ++t) acc += p[(size_t)t * DD];
      cap_avg[c * DD + d] = acc * (1.0f / CL);
    }
  }
}

// ---------------- K2 (merged img+cap): h = tanh(avg@Wg+bg)*Wc
__global__ void k_hvec2(const float* __restrict__ img_avg, const float* __restrict__ cap_avg,
                        const float* __restrict__ vWg, const float* __restrict__ vbg,
                        const float* __restrict__ vWc, const float* __restrict__ tWg,
                        const float* __restrict__ tbg, const float* __restrict__ tWc,
                        float* __restrict__ h_img, float* __restrict__ h_cap) {
  __shared__ float av[DD];
  int bid = blockIdx.x;
  const float* avg;
  const float* Wg;
  const float* bg;
  const float* Wc;
  float* h;
  if (bid < 256) {
    avg = img_avg; Wg = vWg; bg = vbg; Wc = vWc; h = h_img;
  } else {
    avg = cap_avg; Wg = tWg; bg = tbg; Wc = tWc; h = h_cap; bid -= 256;
  }
  int b = bid >> 2;
  int dc = bid & 3;
  int tid = threadIdx.x;
  for (int i = tid; i < DD; i += 256) av[i] = avg[b * DD + i];
  __syncthreads();
  int d = dc * 256 + tid;
  float acc = 0.f;
  for (int k = 0; k < DD; k += 4) {
    float4 a4 = *(const float4*)&av[k];
    acc += a4.x * Wg[(size_t)(k + 0) * DD + d];
    acc += a4.y * Wg[(size_t)(k + 1) * DD + d];
    acc += a4.z * Wg[(size_t)(k + 2) * DD + d];
    acc += a4.w * Wg[(size_t)(k + 3) * DD + d];
  }
  h[b * DD + d] = tanhf(acc + bg[d]) * Wc[d];
}

// ---------------- K3 (MFMA, merged img+cap): partial logits
__global__ void k_logits2(const unsigned short* __restrict__ Ai, const unsigned short* __restrict__ Wi,
                          const float* __restrict__ bli, const float* __restrict__ hi,
                          float* __restrict__ pi,
                          const unsigned short* __restrict__ Ac, const unsigned short* __restrict__ Wc2,
                          const float* __restrict__ blc, const float* __restrict__ hc,
                          float* __restrict__ pc) {
  int tid = threadIdx.x;
  int lane = tid & 63, w = tid >> 6;
  int lrow = lane & 15, lk = (lane >> 4) * 8, rsub = (lane >> 4) * 4;
  int bx = blockIdx.x;
  const unsigned short* Abf;
  const unsigned short* WT;
  const float* bl;
  const float* h;
  float* partial;
  int rb, rowsPerBatch;
  if (bx < 196) {
    Abf = Ai; WT = Wi; bl = bli; h = hi; partial = pi; rb = bx * 64; rowsPerBatch = TT;
  } else {
    Abf = Ac; WT = Wc2; bl = blc; h = hc; partial = pc; rb = (bx - 196) * 64; rowsPerBatch = CL;
  }
  int c0 = blockIdx.y * 64;
  const unsigned short* ap = Abf + (size_t)(rb + w * 16 + lrow) * DD;
  f32x4 acc[4] = {};
  for (int k0 = 0; k0 < DD; k0 += 32) {
    bfrag a = *(const bfrag*)(ap + k0 + lk);
#pragma unroll
    for (int i = 0; i < 4; ++i) {
      bfrag bb = *(const bfrag*)(WT + (size_t)(c0 + i * 16 + lrow) * DD + k0 + lk);
      acc[i] = MFMA(a, bb, acc[i]);
    }
  }
#pragma unroll
  for (int r = 0; r < 4; ++r) {
    int row = rb + w * 16 + rsub + r;
    int bb2 = row / rowsPerBatch;
    float s = 0.f;
#pragma unroll
    for (int i = 0; i < 4; ++i) {
      int col = c0 + i * 16 + lrow;
      s += tanhf(acc[i][r] + bl[col]) * h[bb2 * DD + col];
    }
    s += __shfl_xor(s, 1, 64);
    s += __shfl_xor(s, 2, 64);
    s += __shfl_xor(s, 4, 64);
    s += __shfl_xor(s, 8, 64);
    if (lrow == 0) partial[(size_t)row * 16 + blockIdx.y] = s;
  }
}

// -------- K4 (merged img+cap): finish global attention pooling
__global__ void k_finish2(const float* __restrict__ pi, const float* __restrict__ bci,
                          const float* __restrict__ Xi, long bsi, int Ri, float* __restrict__ oi,
                          const float* __restrict__ pc, const float* __restrict__ bcc,
                          const float* __restrict__ Xc, long bsc, int Rc, float* __restrict__ oc) {
  __shared__ float w[200];
  __shared__ float red[8];
  int bid = blockIdx.x, tid = threadIdx.x;
  const float* partial;
  const float* bc;
  const float* Xbase;
  long batchStride;
  int R, b;
  float* outG;
  if (bid < 64) {
    partial = pi; bc = bci; Xbase = Xi; batchStride = bsi; R = Ri; outG = oi; b = bid;
  } else {
    partial = pc; bc = bcc; Xbase = Xc; batchStride = bsc; R = Rc; outG = oc; b = bid - 64;
  }
  for (int t = tid; t < R; t += 256) {
    const float* pp = &partial[((size_t)b * R + t) * 16];
    float s = bc[0];
#pragma unroll
    for (int u = 0; u < 16; ++u) s += pp[u];
    w[t] = s;
  }
  __syncthreads();
  float m = -1e30f;
  for (int t = tid; t < R; t += 256) m = fmaxf(m, w[t]);
#pragma unroll
  for (int mm = 32; mm; mm >>= 1) m = fmaxf(m, __shfl_xor(m, mm, 64));
  if ((tid & 63) == 0) red[tid >> 6] = m;
  __syncthreads();
  m = fmaxf(fmaxf(red[0], red[1]), fmaxf(red[2], red[3]));
  __syncthreads();
  for (int t = tid; t < R; t += 256) w[t] = expf(w[t] - m);
  __syncthreads();
  const float* xb = Xbase + (size_t)b * batchStride;
  float acc[4];
  float ss = 0.f;
#pragma unroll
  for (int c4 = 0; c4 < 4; ++c4) {
    int d = tid + c4 * 256;
    float a = 0.f;
    for (int t = 0; t < R; ++t) a += w[t] * xb[(size_t)t * DD + d];
    acc[c4] = a;
    ss += a * a;
  }
  ss = warp_reduce_sum64(ss);
  if ((tid & 63) == 0) red[tid >> 6] = ss;
  __syncthreads();
  ss = red[0] + red[1] + red[2] + red[3];
  float rn = 1.0f / fmaxf(sqrtf(ss), EPSN);
#pragma unroll
  for (int c4 = 0; c4 < 4; ++c4) outG[(size_t)b * DD + tid + c4 * 256] = acc[c4] * rn;
}

// -------- K5 (MFMA): sim_glo[p] = l2norm((ig[b]-cg[c])^2 @ W_glo + b_glo)
__global__ void k_simglo_m(const float* __restrict__ ig, const float* __restrict__ cg,
                           const unsigned short* __restrict__ wgloT,
                           const float* __restrict__ bgl, float* __restrict__ simglo) {
  __shared__ unsigned short aL[64 * 40];  // [64 rows][40 u16], 32 used
  int tid = threadIdx.x;
  int lane = tid & 63, w = tid >> 6;
  int lrow = lane & 15, lk = (lane >> 4) * 8, rsub = (lane >> 4) * 4;
  int b = blockIdx.x;
  int srow = tid >> 2, skq = tid & 3;
  f32x4 acc[16] = {};
  for (int k0 = 0; k0 < DD; k0 += 32) {
    // stage diff^2 bf16 for 64 pairs x 32 k
    const float* ip = ig + (size_t)b * DD + k0 + skq * 8;
    const float* cp = cg + (size_t)srow * DD + k0 + skq * 8;
    float4 i0 = *(const float4*)ip;
    float4 i1 = *(const float4*)(ip + 4);
    float4 c0 = *(const float4*)cp;
    float4 c1 = *(const float4*)(cp + 4);
    float d0 = i0.x - c0.x, d1 = i0.y - c0.y, d2 = i0.z - c0.z, d3 = i0.w - c0.w;
    float d4 = i1.x - c1.x, d5 = i1.y - c1.y, d6 = i1.z - c1.z, d7 = i1.w - c1.w;
    uint4 o;
    o.x = (unsigned int)f2b(d0 * d0) | ((unsigned int)f2b(d1 * d1) << 16);
    o.y = (unsigned int)f2b(d2 * d2) | ((unsigned int)f2b(d3 * d3) << 16);
    o.z = (unsigned int)f2b(d4 * d4) | ((unsigned int)f2b(d5 * d5) << 16);
    o.w = (unsigned int)f2b(d6 * d6) | ((unsigned int)f2b(d7 * d7) << 16);
    __syncthreads();  // prior chunk reads done
    *(uint4*)&aL[srow * 40 + skq * 8] = o;
    __syncthreads();
    bfrag af = *(const bfrag*)&aL[(w * 16 + lrow) * 40 + lk];
#pragma unroll
    for (int ct = 0; ct < 16; ++ct) {
      bfrag bb = *(const bfrag*)(wgloT + (size_t)(ct * 16 + lrow) * DD + k0 + lk);
      acc[ct] = MFMA(af, bb, acc[ct]);
    }
  }
  float bglv[16];
#pragma unroll
  for (int ct = 0; ct < 16; ++ct) bglv[ct] = bgl[ct * 16 + lrow];
#pragma unroll
  for (int r = 0; r < 4; ++r) {
    int crow = w * 16 + rsub + r;
    float vv[16];
    float ssq = 0.f;
#pragma unroll
    for (int ct = 0; ct < 16; ++ct) {
      float v = acc[ct][r] + bglv[ct];
      vv[ct] = v;
      ssq += v * v;
    }
    ssq += __shfl_xor(ssq, 1, 64);
    ssq += __shfl_xor(ssq, 2, 64);
    ssq += __shfl_xor(ssq, 4, 64);
    ssq += __shfl_xor(ssq, 8, 64);
    float rn = 1.0f / fmaxf(sqrtf(ssq), EPSN);
    float* op = simglo + ((size_t)b * 64 + crow) * SS;
#pragma unroll
    for (int ct = 0; ct < 16; ++ct) op[ct * 16 + lrow] = vv[ct] * rn;
  }
}

// -------- K6 (+wkbq fold): MT_bf16[t] = A_t @ B_t^T (256x256), bf16 out; blocks 48..50 wkbq
__global__ void k_mmatb(const float* __restrict__ Wa, const float* __restrict__ Wb,
                        unsigned short* __restrict__ M, const float* __restrict__ bq,
                        float* __restrict__ wkbqv) {
  __shared__ float a_lds[32][68];
  __shared__ float b_lds[32][68];
  __shared__ float bv[SS];
  int tid = threadIdx.x;
  if (blockIdx.x >= 48) {
    int t = blockIdx.x - 48;
    const float* wk = Wb + (size_t)t * SS * SS;
    bv[tid] = bq[t * SS + tid];
    __syncthreads();
    float acc = 0.f;
    for (int j = 0; j < SS; j += 4) {
      float4 wv = *(const float4*)&wk[(size_t)tid * SS + j];
      float4 b4 = *(const float4*)&bv[j];
      acc += wv.x * b4.x + wv.y * b4.y + wv.z * b4.z + wv.w * b4.w;
    }
    wkbqv[t * SS + tid] = acc;
    return;
  }
  int t = blockIdx.x >> 4;
  int dt = (blockIdx.x >> 2) & 3, et = blockIdx.x & 3;
  int d0 = dt * 64, e0 = et * 64;
  const float* wq = Wa + (size_t)t * SS * SS;
  const float* wk = Wb + (size_t)t * SS * SS;
  int ty = tid >> 4, tx = tid & 15;
  int s_rr = tid >> 2, s_kq = tid & 3;
  float acc[4][4] = {};
  for (int j0 = 0; j0 < SS; j0 += 32) {
    float4 q0 = *(const float4*)&wq[(size_t)(d0 + s_rr) * SS + j0 + s_kq * 8];
    float4 q1 = *(const float4*)&wq[(size_t)(d0 + s_rr) * SS + j0 + s_kq * 8 + 4];
    float4 k0v = *(const float4*)&wk[(size_t)(e0 + s_rr) * SS + j0 + s_kq * 8];
    float4 k1v = *(const float4*)&wk[(size_t)(e0 + s_rr) * SS + j0 + s_kq * 8 + 4];
    __syncthreads();
    float qa[8] = {q0.x, q0.y, q0.z, q0.w, q1.x, q1.y, q1.z, q1.w};
    float ka[8] = {k0v.x, k0v.y, k0v.z, k0v.w, k1v.x, k1v.y, k1v.z, k1v.w};
#pragma unroll
    for (int u = 0; u < 8; ++u) {
      a_lds[s_kq * 8 + u][s_rr] = qa[u];
      b_lds[s_kq * 8 + u][s_rr] = ka[u];
    }
    __syncthreads();
#pragma unroll
    for (int kk = 0; kk < 32; ++kk) {
      float4 a4 = *(const float4*)&a_lds[kk][ty * 4];
      float4 b4 = *(const float4*)&b_lds[kk][tx * 4];
      float av[4] = {a4.x, a4.y, a4.z, a4.w};
      float bvv[4] = {b4.x, b4.y, b4.z, b4.w};
#pragma unroll
      for (int i = 0; i < 4; ++i)
#pragma unroll
        for (int j = 0; j < 4; ++j) acc[i][j] += av[i] * bvv[j];
    }
  }
#pragma unroll
  for (int i = 0; i < 4; ++i) {
    unsigned int lo = (unsigned int)f2b(acc[i][0]) | ((unsigned int)f2b(acc[i][1]) << 16);
    unsigned int hi = (unsigned int)f2b(acc[i][2]) | ((unsigned int)f2b(acc[i][3]) << 16);
    uint2 o = make_uint2(lo, hi);
    *(uint2*)(M + (size_t)t * SS * SS + (size_t)(d0 + ty * 4 + i) * SS + e0 + tx * 4) = o;
  }
}

// -------- fused img prep: row-major bf16 + transposed padded bf16 (one img read)
__global__ void k_imgprep(const float* __restrict__ img, unsigned short* __restrict__ row_bf,
                          unsigned short* __restrict__ tr_bf) {
  __shared__ float t[32][33];
  int b = blockIdx.z;
  int t0 = blockIdx.y * 32, d0 = blockIdx.x * 32;
  int tx = threadIdx.x & 31, ty = threadIdx.x >> 5;
#pragma unroll
  for (int u = 0; u < 4; ++u) {
    int tt = t0 + ty + u * 8;
    float v = (tt < TT) ? img[((size_t)b * NTOK + 1 + tt) * DD + d0 + tx] : 0.f;
    t[ty + u * 8][tx] = v;
    if (tt < TT) row_bf[((size_t)b * TT + tt) * DD + d0 + tx] = f2b(v);
  }
  __syncthreads();
#pragma unroll
  for (int u = 0; u < 4; ++u)
    tr_bf[((size_t)b * DD + d0 + ty + u * 8) * TP + t0 + tx] = f2b(t[tx][ty + u * 8]);
}

// -------- K6c (MFMA): gram_bf16[b] = imgTok_b @ imgTok_b^T in [208][224] zero-padded
__global__ void k_gram_mfma(const unsigned short* __restrict__ img_bf,
                            unsigned short* __restrict__ gram) {
  int tid = threadIdx.x;
  int lane = tid & 63, w = tid >> 6;
  int lrow = lane & 15, lk = (lane >> 4) * 8, rsub = (lane >> 4) * 4;
  int bimg = blockIdx.x;
  int rb = blockIdx.y * 64, cb = blockIdx.z * 64;
  const unsigned short* X = img_bf + (size_t)bimg * TT * DD;
  int ra = rb + w * 16 + lrow;
  if (ra > TT - 1) ra = TT - 1;
  f32x4 acc[4] = {};
  for (int k0 = 0; k0 < DD; k0 += 32) {
    bfrag a = *(const bfrag*)(X + (size_t)ra * DD + k0 + lk);
#pragma unroll
    for (int i = 0; i < 4; ++i) {
      int cc = cb + i * 16 + lrow;
      if (cc > TT - 1) cc = TT - 1;
      bfrag bb = *(const bfrag*)(X + (size_t)cc * DD + k0 + lk);
      acc[i] = MFMA(a, bb, acc[i]);
    }
  }
  unsigned short* Gp = gram + (size_t)bimg * 208 * TP;
#pragma unroll
  for (int i = 0; i < 4; ++i) {
    int cc = cb + i * 16 + lrow;
#pragma unroll
    for (int r = 0; r < 4; ++r) {
      int rr = rb + w * 16 + rsub + r;
      if (rr < 208 && cc < TP)
        Gp[(size_t)rr * TP + cc] = (rr < TT && cc < TT) ? f2b(acc[i][r]) : 0;
    }
  }
}

// -------- cast f32 -> bf16 (same layout)
__global__ void k_castb(const float* __restrict__ s, unsigned short* __restrict__ d, int n4) {
  int i = blockIdx.x * 256 + threadIdx.x;
  if (i < n4) {
    float4 v = *(const float4*)(s + (size_t)i * 4);
    uint2 o;
    o.x = (unsigned int)f2b(v.x) | ((unsigned int)f2b(v.y) << 16);
    o.y = (unsigned int)f2b(v.z) | ((unsigned int)f2b(v.w) << 16);
    *(uint2*)(d + (size_t)i * 4) = o;
  }
}

// -------- all transpose-casts in one launch (linear tile decode)
__global__ void k_tcast_all(const float* __restrict__ vWl, const float* __restrict__ tWl,
                            const float* __restrict__ sWg, const float* __restrict__ Wloc,
                            const float* __restrict__ Wglo,
                            unsigned short* __restrict__ wlT_v, unsigned short* __restrict__ wlT_t,
                            unsigned short* __restrict__ wgT3, unsigned short* __restrict__ wlocT,
                            unsigned short* __restrict__ wgloT) {
  __shared__ float t[32][33];
  int id = blockIdx.x;
  const float* s;
  unsigned short* d;
  int R, C;
  if (id < 1024) {
    s = vWl; d = wlT_v; R = 1024; C = 1024;
  } else if (id < 2048) {
    s = tWl; d = wlT_t; R = 1024; C = 1024; id -= 1024;
  } else if (id < 2240) {
    id -= 2048;
    int tb = id >> 6; id &= 63;
    s = sWg + (size_t)tb * 65536; d = wgT3 + (size_t)tb * 65536; R = 256; C = 256;
  } else if (id < 2496) {
    s = Wloc; d = wlocT; R = 1024; C = 256; id -= 2240;
  } else {
    s = Wglo; d = wgloT; R = 1024; C = 256; id -= 2496;
  }
  int ct = C >> 5;
  int r0 = (id / ct) * 32, c0 = (id % ct) * 32;
  int tx = threadIdx.x & 31, ty = threadIdx.x >> 5;
#pragma unroll
  for (int u = 0; u < 4; ++u)
    t[ty + u * 8][tx] = s[(size_t)(r0 + ty + u * 8) * C + c0 + tx];
  __syncthreads();
#pragma unroll
  for (int u = 0; u < 4; ++u)
    d[(size_t)(c0 + ty + u * 8) * R + r0 + tx] = f2b(t[tx][ty + u * 8]);
}

// -------- K7: per-(img,cap) pair mega kernel (v11: = v10 + XCD swizzle)
__global__ __launch_bounds__(256, 4) void k_pair(
    const float* __restrict__ b_loc, const float* __restrict__ simglo,
    const float* __restrict__ wkbq, const float* __restrict__ bg3,
    const float* __restrict__ W_eval, const float* __restrict__ b_eval,
    const unsigned short* __restrict__ cap_bf, const unsigned short* __restrict__ img_bf,
    const unsigned short* __restrict__ imgT_bf, const unsigned short* __restrict__ gram_bf,
    const unsigned short* __restrict__ wlocT_bf, const unsigned short* __restrict__ mt_bf,
    const unsigned short* __restrict__ wgT_bf, float* __restrict__ out) {
  extern __shared__ char smem[];

  int tid = threadIdx.x;
  int lane = tid & 63, w = tid >> 6;
  int lrow = lane & 15;        // MFMA row/col select
  int lk = (lane >> 4) * 8;    // MFMA k-offset
  int rsub = (lane >> 4) * 4;  // D-frag row base
  int p = ((blockIdx.x & 7) << 9) | (blockIdx.x >> 3);  // XCD-contiguous pair blocks
  int b = p >> 6, c = p & 63;
  const unsigned short* imgR = img_bf + (size_t)b * TT * DD;
  const unsigned short* capB = cap_bf + (size_t)c * CL * DD;
  char* attnT_b = smem + OFF_ATTNT;

  // ================ Phase A: S = leaky(imgTok.cap) MFMA; epilogue in registers
  {
    f32x4 acc[4][2] = {};
    for (int k0 = 0; k0 < DD; k0 += 32) {
      bfrag bq0 = *(const bfrag*)(capB + (size_t)lrow * DD + k0 + lk);
      bfrag bq1 = *(const bfrag*)(capB + (size_t)(16 + lrow) * DD + k0 + lk);
#pragma unroll
      for (int i = 0; i < 4; ++i) {
        int tt = w + 4 * i;
        if (tt < 13) {
          int t = tt * 16 + lrow;
          bfrag a = {0, 0, 0, 0, 0, 0, 0, 0};
          if (t < TT) a = *(const bfrag*)(imgR + (size_t)t * DD + k0 + lk);
          acc[i][0] = MFMA(a, bq0, acc[i][0]);
          acc[i][1] = MFMA(a, bq1, acc[i][1]);
        }
      }
    }
    float mx0 = -1e30f, mx1 = -1e30f;
#pragma unroll
    for (int i = 0; i < 4; ++i) {
      int tt = w + 4 * i;
      if (tt < 13) {
#pragma unroll
        for (int r = 0; r < 4; ++r) {
          int t = tt * 16 + rsub + r;
          float v0 = acc[i][0][r];
          v0 = v0 < 0.f ? 0.1f * v0 : v0;
          float v1 = acc[i][1][r];
          v1 = v1 < 0.f ? 0.1f * v1 : v1;
          float s2 = v0 * v0 + v1 * v1;
          s2 += __shfl_xor(s2, 1, 64);
          s2 += __shfl_xor(s2, 2, 64);
          s2 += __shfl_xor(s2, 4, 64);
          s2 += __shfl_xor(s2, 8, 64);
          float rn = 1.0f / fmaxf(sqrtf(s2), EPSN);
          v0 *= rn;
          v1 *= rn;
          acc[i][0][r] = v0;
          acc[i][1][r] = v1;
          if (t < TT) {
            mx0 = fmaxf(mx0, v0);
            mx1 = fmaxf(mx1, v1);
          }
        }
      }
    }
    mx0 = fmaxf(mx0, __shfl_xor(mx0, 16, 64));
    mx0 = fmaxf(mx0, __shfl_xor(mx0, 32, 64));
    mx1 = fmaxf(mx1, __shfl_xor(mx1, 16, 64));
    mx1 = fmaxf(mx1, __shfl_xor(mx1, 32, 64));
    float* wmax = (float*)(smem + OFF_WMAX);
    if ((lane >> 4) == 0) {
      wmax[w * 32 + lrow] = mx0;
      wmax[w * 32 + 16 + lrow] = mx1;
    }
    __syncthreads();
    mx0 = fmaxf(fmaxf(wmax[lrow], wmax[32 + lrow]), fmaxf(wmax[64 + lrow], wmax[96 + lrow]));
    mx1 = fmaxf(fmaxf(wmax[16 + lrow], wmax[48 + lrow]),
                fmaxf(wmax[80 + lrow], wmax[112 + lrow]));
#pragma unroll
    for (int i = 0; i < 4; ++i) {
      int tt = w + 4 * i;
#pragma unroll
      for (int r = 0; r < 4; ++r) {
        int t = tt * 16 + rsub + r;
        if (t < TP) {
          unsigned short e0 = 0, e1 = 0;
          if (t < TT) {
            e0 = f2b(expf(SMOOTHF * (acc[i][0][r] - mx0)));
            e1 = f2b(expf(SMOOTHF * (acc[i][1][r] - mx1)));
          }
          *(unsigned short*)(attnT_b + lrow * 464 + t * 2) = e0;
          *(unsigned short*)(attnT_b + (16 + lrow) * 464 + t * 2) = e1;
        }
      }
    }
  }
  __syncthreads();

  // ================ norm via Gram (MFMA)
  {
    float* qn = (float*)(smem + OFF_QN);
    float* nrmS = (float*)(smem + OFF_NRMS);
    const unsigned short* gb = gram_bf + (size_t)b * 208 * TP;
    float part0 = 0.f, part1 = 0.f;
#pragma unroll
    for (int i = 0; i < 4; ++i) {
      int tt = w + 4 * i;
      if (tt < 13) {
        f32x4 y0 = {0.f, 0.f, 0.f, 0.f}, y1 = {0.f, 0.f, 0.f, 0.f};
        for (int t0 = 0; t0 < TP; t0 += 32) {
          bfrag a = *(const bfrag*)(gb + (size_t)(tt * 16 + lrow) * TP + t0 + lk);
          bfrag b0 = *(const bfrag*)(attnT_b + lrow * 464 + (t0 + lk) * 2);
          bfrag b1 = *(const bfrag*)(attnT_b + (16 + lrow) * 464 + (t0 + lk) * 2);
          y0 = MFMA(a, b0, y0);
          y1 = MFMA(a, b1, y1);
        }
#pragma unroll
        for (int r = 0; r < 4; ++r) {
          int t = tt * 16 + rsub + r;
          if (t < TT) {
            part0 += y0[r] * b2f(*(const unsigned short*)(attnT_b + lrow * 464 + t * 2));
            part1 += y1[r] * b2f(*(const unsigned short*)(attnT_b + (16 + lrow) * 464 + t * 2));
          }
        }
      }
    }
    part0 += __shfl_xor(part0, 16, 64);
    part0 += __shfl_xor(part0, 32, 64);
    part1 += __shfl_xor(part1, 16, 64);
    part1 += __shfl_xor(part1, 32, 64);
    if ((lane >> 4) == 0) {
      qn[w * 32 + lrow] = part0;
      qn[w * 32 + 16 + lrow] = part1;
    }
    __syncthreads();
    if (tid < 32)
      nrmS[tid] = 1.0f / fmaxf(sqrtf(qn[tid] + qn[32 + tid] + qn[64 + tid] + qn[96 + tid]), EPSN);
    __syncthreads();
  }

  // ================ Phase W: ctx (MFMA, d-tile split) -> diff^2 -> @W_loc
  f32x4 accW[2][4] = {};
  {
    char* wtile_b = smem + OFF_WTILE;
    float* nrmS = (float*)(smem + OFF_NRMS);
    float nrm0 = nrmS[lrow], nrm1 = nrmS[16 + lrow];
    for (int d0 = 0; d0 < DD; d0 += 128) {
#pragma unroll
      for (int i = 0; i < 2; ++i) {
        f32x4 c2[2] = {};
        int dt = w + 4 * i;
        const unsigned short* ib = imgT_bf + ((size_t)b * DD + d0 + dt * 16 + lrow) * TP;
        for (int t0 = 0; t0 < TP; t0 += 32) {
          bfrag b0 = *(const bfrag*)(attnT_b + lrow * 464 + (t0 + lk) * 2);
          bfrag b1 = *(const bfrag*)(attnT_b + (16 + lrow) * 464 + (t0 + lk) * 2);
          bfrag a = *(const bfrag*)(ib + t0 + lk);
          c2[0] = MFMA(a, b0, c2[0]);
          c2[1] = MFMA(a, b1, c2[1]);
        }
        if (i == 0) __syncthreads();
        int dl = dt * 16 + rsub;
#pragma unroll
        for (int qt = 0; qt < 2; ++qt) {
          int q = qt * 16 + lrow;
          uint2 cu = *(const uint2*)(capB + (size_t)q * DD + d0 + dl);
          float cf0 = b2f(cu.x & 0xffff), cf1 = b2f(cu.x >> 16);
          float cf2 = b2f(cu.y & 0xffff), cf3 = b2f(cu.y >> 16);
          float rn = qt ? nrm1 : nrm0;
          float v0 = c2[qt][0] * rn - cf0;
          float v1 = c2[qt][1] * rn - cf1;
          float v2 = c2[qt][2] * rn - cf2;
          float v3 = c2[qt][3] * rn - cf3;
          unsigned int lo = (unsigned int)f2b(v0 * v0) | ((unsigned int)f2b(v1 * v1) << 16);
          unsigned int hi = (unsigned int)f2b(v2 * v2) | ((unsigned int)f2b(v3 * v3) << 16);
          *(uint2*)(wtile_b + q * 272 + dl * 2) = make_uint2(lo, hi);
        }
      }
      __syncthreads();
      for (int kc = 0; kc < 4; ++kc) {
        bfrag a0 = *(const bfrag*)(wtile_b + lrow * 272 + (kc * 32 + lk) * 2);
        bfrag a1 = *(const bfrag*)(wtile_b + (16 + lrow) * 272 + (kc * 32 + lk) * 2);
#pragma unroll
        for (int sti = 0; sti < 4; ++sti) {
          int s = (w * 4 + sti) * 16 + lrow;
          bfrag bb = *(const bfrag*)(wlocT_bf + (size_t)s * DD + d0 + kc * 32 + lk);
          accW[0][sti] = MFMA(a0, bb, accW[0][sti]);
          accW[1][sti] = MFMA(a1, bb, accW[1][sti]);
        }
      }
    }
  }

  // ================ assembly: l2norm(sim_loc)+bias -> seA rows 1..32; row 0 simglo
  {
    char* seA_b = smem + OFF_SEA;
    float* qn = (float*)(smem + OFF_QN);
    float* rnq = (float*)(smem + OFF_RNQ);
    __syncthreads();
    float blv[4];
#pragma unroll
    for (int sti = 0; sti < 4; ++sti) blv[sti] = b_loc[(w * 4 + sti) * 16 + lrow];
    float ss[2][4];
#pragma unroll
    for (int qt = 0; qt < 2; ++qt)
#pragma unroll
      for (int r = 0; r < 4; ++r) {
        float s2 = 0.f;
#pragma unroll
        for (int sti = 0; sti < 4; ++sti) {
          float v = accW[qt][sti][r] + blv[sti];
          s2 += v * v;
        }
        s2 += __shfl_xor(s2, 1, 64);
        s2 += __shfl_xor(s2, 2, 64);
        s2 += __shfl_xor(s2, 4, 64);
        s2 += __shfl_xor(s2, 8, 64);
        ss[qt][r] = s2;
      }
    if (lrow == 0) {
#pragma unroll
      for (int qt = 0; qt < 2; ++qt)
#pragma unroll
        for (int r = 0; r < 4; ++r)
          qn[w * 32 + qt * 16 + rsub + r] = ss[qt][r];
    }
    __syncthreads();
    if (tid < 32)
      rnq[tid] = 1.0f / fmaxf(sqrtf(qn[tid] + qn[32 + tid] + qn[64 + tid] + qn[96 + tid]), EPSN);
    __syncthreads();
#pragma unroll
    for (int qt = 0; qt < 2; ++qt)
#pragma unroll
      for (int r = 0; r < 4; ++r) {
        int q = qt * 16 + rsub + r;
        float rn = rnq[q];
#pragma unroll
        for (int sti = 0; sti < 4; ++sti) {
          int s = (w * 4 + sti) * 16 + lrow;
          float v = (accW[qt][sti][r] + blv[sti]) * rn;
          *(unsigned short*)(seA_b + (1 + q) * 528 + s * 2) = f2b(v);
        }
      }
    if (tid < 64) {
      float4 g4 = *(const float4*)&simglo[(size_t)p * SS + tid * 4];
      unsigned int lo = (unsigned int)f2b(g4.x) | ((unsigned int)f2b(g4.y) << 16);
      unsigned int hi = (unsigned int)f2b(g4.z) | ((unsigned int)f2b(g4.w) << 16);
      *(uint2*)(seA_b + tid * 8) = make_uint2(lo, hi);
    }
    __syncthreads();
  }

  // ================ SGR x3 (33-row seA; aliased pad reads feed only discarded outputs)
  {
    char* seA_b = smem + OFF_SEA;
    char* Gc_b = smem + OFF_R1;
    char* XT_b = smem + OFF_R1;
    float* Ef = (float*)(smem + OFF_R1);
    char* Eb = smem + OFF_EB;
    float* wkq = (float*)(smem + OFF_WKQ);
    float* vbuf = (float*)(smem + OFF_VBUF);

    for (int step = 0; step < 3; ++step) {
      const unsigned short* mstep = mt_bf + (size_t)step * SS * SS;
      const unsigned short* wstep = wgT_bf + (size_t)step * SS * SS;
      wkq[tid] = wkbq[step * SS + tid];
      __syncthreads();
      if (tid < 132) {
        int m = tid >> 2, qq = tid & 3;
        float a = 0.f;
        for (int e = qq * 64; e < qq * 64 + 64; e += 2) {
          unsigned int u = *(const unsigned int*)(seA_b + m * 528 + e * 2);
          a += b2f(u & 0xffff) * wkq[e] + b2f(u >> 16) * wkq[e + 1];
        }
        a += __shfl_xor(a, 1, 64);
        a += __shfl_xor(a, 2, 64);
        if (qq == 0) vbuf[m] = a;
      }
      f32x4 aE[3] = {};
      for (int ec = 0; ec < 4; ++ec) {
        f32x4 aGc[3] = {};
        for (int kc = 0; kc < 8; ++kc) {
          int k = kc * 32 + lk;
          bfrag bb = *(const bfrag*)(mstep + (size_t)(ec * 64 + w * 16 + lrow) * SS + k);
#pragma unroll
          for (int mt = 0; mt < 3; ++mt) {
            bfrag af = *(const bfrag*)(seA_b + (mt * 16 + lrow) * 528 + k * 2);
            aGc[mt] = MFMA(af, bb, aGc[mt]);
          }
        }
        __syncthreads();
#pragma unroll
        for (int mt = 0; mt < 3; ++mt)
#pragma unroll
          for (int r = 0; r < 4; ++r)
            *(unsigned short*)(Gc_b + (mt * 16 + rsub + r) * 144 + (w * 16 + lrow) * 2) =
                f2b(aGc[mt][r]);
        __syncthreads();
#pragma unroll
        for (int kc = 0; kc < 2; ++kc) {
          int k = kc * 32 + lk;
#pragma unroll
          for (int ti = 0; ti < 3; ++ti) {
            int tile = w + ti * 4;
            if (tile < 9) {
              int mtE = tile / 3, ntE = tile - mtE * 3;
              bfrag ga = *(const bfrag*)(Gc_b + (mtE * 16 + lrow) * 144 + k * 2);
              bfrag sb = *(const bfrag*)(seA_b + (ntE * 16 + lrow) * 528 + (ec * 64 + k) * 2);
              aE[ti] = MFMA(ga, sb, aE[ti]);
            }
          }
        }
      }
      __syncthreads();
#pragma unroll
      for (int ti = 0; ti < 3; ++ti) {
        int tile = w + ti * 4;
        if (tile < 9) {
          int mtE = tile / 3, ntE = tile - mtE * 3;
          int n0 = mtE * 16 + rsub, m = ntE * 16 + lrow;
#pragma unroll
          for (int r = 0; r < 4; ++r)
            if (n0 + r < NN && m < NN) Ef[(n0 + r) * 34 + m] = aE[ti][r] + vbuf[m];
        }
      }
      __syncthreads();
      if (tid < NN) {
        float mx = -1e30f;
        for (int mm = 0; mm < NN; ++mm) mx = fmaxf(mx, Ef[tid * 34 + mm]);
        float sum = 0.f;
        for (int mm = 0; mm < NN; ++mm) {
          float e = expf(Ef[tid * 34 + mm] - mx);
          Ef[tid * 34 + mm] = e;
          sum += e;
        }
        float rs = 1.0f / sum;
        for (int mm = 0; mm < NN; ++mm) Ef[tid * 34 + mm] *= rs;
      }
      __syncthreads();
      for (int idx = tid; idx < 33 * 36; idx += 256) {
        int n = idx / 36, mp = (idx - n * 36) * 2;
        unsigned int lo = (mp < NN) ? (unsigned int)f2b(Ef[n * 34 + mp]) : 0u;
        unsigned int hi = (mp + 1 < NN) ? (unsigned int)f2b(Ef[n * 34 + mp + 1]) : 0u;
        *(unsigned int*)(Eb + n * 144 + mp * 2) = lo | (hi << 16);
      }
      __syncthreads();
      unsigned int oPk[4][3][2];
#pragma unroll
      for (int sc = 0; sc < 4; ++sc) {
        f32x4 aX[3] = {};
        for (int kc = 0; kc < 8; ++kc) {
          int k = kc * 32 + lk;
          bfrag bb = *(const bfrag*)(wstep + (size_t)(sc * 64 + w * 16 + lrow) * SS + k);
#pragma unroll
          for (int mt = 0; mt < 3; ++mt) {
            bfrag af = *(const bfrag*)(seA_b + (mt * 16 + lrow) * 528 + k * 2);
            aX[mt] = MFMA(af, bb, aX[mt]);
          }
        }
        __syncthreads();
#pragma unroll
        for (int mt = 0; mt < 3; ++mt) {
          unsigned int lo = (unsigned int)f2b(aX[mt][0]) | ((unsigned int)f2b(aX[mt][1]) << 16);
          unsigned int hi = (unsigned int)f2b(aX[mt][2]) | ((unsigned int)f2b(aX[mt][3]) << 16);
          *(uint2*)(XT_b + (w * 16 + lrow) * 144 + (mt * 16 + rsub) * 2) = make_uint2(lo, hi);
        }
        *(uint2*)(XT_b + (w * 16 + lrow) * 144 + (48 + rsub) * 2) = make_uint2(0, 0);
        __syncthreads();
        f32x4 aO[3] = {};
#pragma unroll
        for (int kc = 0; kc < 2; ++kc) {
          int k = kc * 32 + lk;
          bfrag xa = *(const bfrag*)(XT_b + (w * 16 + lrow) * 144 + k * 2);
#pragma unroll
          for (int nt = 0; nt < 3; ++nt) {
            bfrag eb = *(const bfrag*)(Eb + (nt * 16 + lrow) * 144 + k * 2);
            aO[nt] = MFMA(xa, eb, aO[nt]);
          }
        }
        float bga[4];
#pragma unroll
        for (int r = 0; r < 4; ++r) bga[r] = bg3[step * SS + sc * 64 + w * 16 + rsub + r];
#pragma unroll
        for (int nt = 0; nt < 3; ++nt) {
          float v0 = fmaxf(aO[nt][0] + bga[0], 0.f);
          float v1 = fmaxf(aO[nt][1] + bga[1], 0.f);
          float v2 = fmaxf(aO[nt][2] + bga[2], 0.f);
          float v3 = fmaxf(aO[nt][3] + bga[3], 0.f);
          oPk[sc][nt][0] = (unsigned int)f2b(v0) | ((unsigned int)f2b(v1) << 16);
          oPk[sc][nt][1] = (unsigned int)f2b(v2) | ((unsigned int)f2b(v3) << 16);
        }
      }
#pragma unroll
      for (int sc = 0; sc < 4; ++sc)
#pragma unroll
        for (int nt = 0; nt < 3; ++nt) {
          int n = nt * 16 + lrow;
          if (n < NN)
            *(uint2*)(seA_b + n * 528 + (sc * 64 + w * 16 + rsub) * 2) =
                make_uint2(oPk[sc][nt][0], oPk[sc][nt][1]);
        }
      __syncthreads();
    }
  }

  // ================ eval: sigmoid(seA[0] @ W_eval + b_eval)
  if (tid < 64) {
    const char* seA_b = smem + OFF_SEA;
    uint2 u = *(const uint2*)(seA_b + tid * 8);
    float4 w4 = *(const float4*)&W_eval[tid * 4];
    float s = b2f(u.x & 0xffff) * w4.x + b2f(u.x >> 16) * w4.y +
              b2f(u.y & 0xffff) * w4.z + b2f(u.y >> 16) * w4.w;
    s = warp_reduce_sum64(s);
    if (tid == 0) out[b * 64 + c] = 1.0f / (1.0f + expf(-(s + b_eval[0])));
  }
}

extern "C" void kernel_launch(void* const* d_in, const int* in_sizes, int n_in,
                              void* d_out, int out_size, void* d_ws, size_t ws_size,
                              hipStream_t stream) {
  (void)in_sizes; (void)n_in; (void)out_size; (void)ws_size;
  const float* img = (const float*)d_in[0];
  const float* cap = (const float*)d_in[1];
  const float* vG_Wl = (const float*)d_in[3];
  const float* vG_bl = (const float*)d_in[4];
  const float* vG_Wg = (const float*)d_in[5];
  const float* vG_bg = (const float*)d_in[6];
  const float* vG_Wc = (const float*)d_in[7];
  const float* vG_bc = (const float*)d_in[8];
  const float* tG_Wl = (const float*)d_in[9];
  const float* tG_bl = (const float*)d_in[10];
  const float* tG_Wg = (const float*)d_in[11];
  const float* tG_bg = (const float*)d_in[12];
  const float* tG_Wc = (const float*)d_in[13];
  const float* tG_bc = (const float*)d_in[14];
  const float* W_loc = (const float*)d_in[15];
  const float* b_loc = (const float*)d_in[16];
  const float* W_glo = (const float*)d_in[17];
  const float* b_glo = (const float*)d_in[18];
  const float* W_eval = (const float*)d_in[19];
  const float* b_eval = (const float*)d_in[20];
  const float* sgr_Wq = (const float*)d_in[21];
  const float* sgr_bq = (const float*)d_in[22];
  const float* sgr_Wk = (const float*)d_in[23];
  const float* sgr_Wg = (const float*)d_in[25];
  const float* sgr_bg = (const float*)d_in[26];
  float* out = (float*)d_out;
  float* ws = (float*)d_ws;
  float* img_avg = ws;
  float* cap_avg = ws + 65536;
  float* h_img = ws + 131072;
  float* h_cap = ws + 196608;
  float* part_img = ws + 262144;
  float* part_cap = ws + 462848;
  float* img_glob = ws + 495616;
  float* cap_glob = ws + 561152;
  float* simglo = ws + 626688;
  float* wkbqv = ws + 1675264;
  // bf16 region (u16 units) starts at float offset 1676032 (16B aligned)
  unsigned short* ub = (unsigned short*)(ws + 1676032);
  unsigned short* mt_bf = ub;                   // 196608
  unsigned short* wgT_bf = ub + 196608;         // 196608 -> 393216
  unsigned short* wlocT_bf = ub + 393216;       // 262144 -> 655360
  unsigned short* cap_bf = ub + 655360;         // 2097152 -> 2752512
  unsigned short* gram_bf = ub + 2752512;       // 2981888 -> 5734400
  unsigned short* imgT_bf = ub + 5734400;       // 14680064 -> 20414464
  unsigned short* img_bf = ub + 20414464;       // 12845056 -> 33259520
  unsigned short* wlT_v = ub + 33259520;        // 1048576 -> 34308096
  unsigned short* wlT_t = ub + 34308096;        // 1048576 -> 35356672
  unsigned short* wgloT = ub + 35356672;        // 262144 -> 35618816

  k_avg<<<128, 256, 0, stream>>>(img, cap, img_avg, cap_avg);
  k_imgprep<<<dim3(32, 7, 64), 256, 0, stream>>>(img, img_bf, imgT_bf);
  k_castb<<<2048, 256, 0, stream>>>(cap, cap_bf, 524288);
  k_tcast_all<<<2752, 256, 0, stream>>>(vG_Wl, tG_Wl, sgr_Wg, W_loc, W_glo,
                                        wlT_v, wlT_t, wgT_bf, wlocT_bf, wgloT);
  k_hvec2<<<512, 256, 0, stream>>>(img_avg, cap_avg, vG_Wg, vG_bg, vG_Wc,
                                   tG_Wg, tG_bg, tG_Wc, h_img, h_cap);
  k_logits2<<<dim3(228, 16), 256, 0, stream>>>(img_bf, wlT_v, vG_bl, h_img, part_img,
                                               cap_bf, wlT_t, tG_bl, h_cap, part_cap);
  k_finish2<<<128, 256, 0, stream>>>(part_img, vG_bc, img + DD, (long)NTOK * DD, TT, img_glob,
                                     part_cap, tG_bc, cap, (long)CL * DD, CL, cap_glob);
  k_simglo_m<<<64, 256, 0, stream>>>(img_glob, cap_glob, wgloT, b_glo, simglo);
  k_mmatb<<<51, 256, 0, stream>>>(sgr_Wk, sgr_Wq, mt_bf, sgr_bq, wkbqv);
  k_gram_mfma<<<dim3(64, 4, 4), 256, 0, stream>>>(img_bf, gram_bf);
  hipFuncSetAttribute((const void*)k_pair, hipFuncAttributeMaxDynamicSharedMemorySize,
                      SMEM_BYTES);
  k_pair<<<4096, 256, SMEM_BYTES, stream>>>(b_loc, simglo, wkbqv, sgr_bg, W_eval, b_eval,
                                            cap_bf, img_bf, imgT_bf, gram_bf, wlocT_bf,
                                            mt_bf, wgT_bf, out);
}

// Round 12
// 1660.851 us; speedup vs baseline: 1.1661x; 1.0340x over previous
//
#include <hip/hip_runtime.h>
#include <hip/hip_bf16.h>
#include <math.h>

#define NI 64
#define NC 64
#define NTOK 197
#define TT 196
#define CL 32
#define DD 1024
#define SS 256
#define NN 33
#define EPSN 1e-12f
#define SMOOTHF 9.0f
#define TP 224   // padded token dim for MFMA K

typedef __attribute__((ext_vector_type(8))) short bfrag;
typedef __attribute__((ext_vector_type(4))) float f32x4;
#define MFMA(a, b, c) __builtin_amdgcn_mfma_f32_16x16x32_bf16((a), (b), (c), 0, 0, 0)

// LDS layout (byte offsets) — phase A/W region (dead before SGR)
#define OFF_ATTNT  0        // [32][232] u16 = 14848
#define OFF_WTILE  14848    // [32][136] u16 = 8704 -> 23552
#define OFF_WMAX   23552    // [4][32] f32 = 512 -> 24064
#define OFF_NRMS   24064    // [32] f32 -> 24192
#define OFF_QN     24192    // [128] f32 -> 24704
#define OFF_RNQ    24704    // [32] f32 -> 24832
// SGR overlays
#define OFF_SEA    0        // [33][264] u16 = 17424 (MFMA reads "rows" to 47 alias EB/R1 ->
                            //  garbage feeds only discarded outputs n,m >= 33)
#define OFF_EB     17424    // [33][72] u16 = 4752 -> 22176 (reads of rows 33..47 alias R1 head)
#define OFF_R1     22176    // Gc 48*144=6912 / XT 64*144=9216 / Ef 33*34*4=4488 -> 31392
#define OFF_WKQ    29088    // [256] f32 -> 30112 (R1 tail after Gc; dead before XT writes)
#define OFF_VBUF   30112    // [36] f32 -> 30256 (ditto)
#define SMEM_BYTES 31392

__device__ __forceinline__ float warp_reduce_sum64(float v) {
#pragma unroll
  for (int m = 32; m > 0; m >>= 1) v += __shfl_xor(v, m, 64);
  return v;
}
__device__ __forceinline__ unsigned short f2b(float f) {
  __hip_bfloat16 h = __float2bfloat16(f);
  return *reinterpret_cast<unsigned short*>(&h);
}
__device__ __forceinline__ float b2f(unsigned short u) {
  union { unsigned int i; float f; } v;
  v.i = ((unsigned int)u) << 16;
  return v.f;
}

// ======== L1 mega-prep: avg | imgprep | castb | tcast_all | mmatb+wkbq ========
__global__ void k_prep(const float* __restrict__ img, const float* __restrict__ cap,
                       float* __restrict__ img_avg, float* __restrict__ cap_avg,
                       unsigned short* __restrict__ row_bf, unsigned short* __restrict__ tr_bf,
                       unsigned short* __restrict__ cap_bf,
                       const float* __restrict__ vWl, const float* __restrict__ tWl,
                       const float* __restrict__ sWg, const float* __restrict__ Wloc,
                       const float* __restrict__ Wglo,
                       unsigned short* __restrict__ wlT_v, unsigned short* __restrict__ wlT_t,
                       unsigned short* __restrict__ wgT3, unsigned short* __restrict__ wlocT,
                       unsigned short* __restrict__ wgloT,
                       const float* __restrict__ Wa, const float* __restrict__ Wb,
                       unsigned short* __restrict__ M, const float* __restrict__ bq,
                       float* __restrict__ wkbqv) {
  __shared__ float shbuf[4608];  // 18432 B peak (mmatb branch)
  int id = blockIdx.x;
  int tid = threadIdx.x;

  if (id < 128) {  // ---- k_avg
    if (id < NI) {
      int b = id;
      for (int d = tid; d < DD; d += 256) {
        float acc = 0.f;
        const float* p = img + ((size_t)b * NTOK + 1) * DD + d;
        for (int t = 0; t < TT; ++t) acc += p[(size_t)t * DD];
        img_avg[b * DD + d] = acc * (1.0f / TT);
      }
    } else {
      int c = id - NI;
      for (int d = tid; d < DD; d += 256) {
        float acc = 0.f;
        const float* p = cap + (size_t)c * CL * DD + d;
        for (int t = 0; t < CL; ++t) acc += p[(size_t)t * DD];
        cap_avg[c * DD + d] = acc * (1.0f / CL);
      }
    }
    return;
  }
  if (id < 14464) {  // ---- imgprep: row bf16 + transposed padded bf16
    id -= 128;
    int bx = id & 31, by = (id >> 5) % 7, b = id / 224;
    float (*t)[33] = (float(*)[33])shbuf;
    int t0 = by * 32, d0 = bx * 32;
    int tx = tid & 31, ty = tid >> 5;
#pragma unroll
    for (int u = 0; u < 4; ++u) {
      int tt = t0 + ty + u * 8;
      float v = (tt < TT) ? img[((size_t)b * NTOK + 1 + tt) * DD + d0 + tx] : 0.f;
      t[ty + u * 8][tx] = v;
      if (tt < TT) row_bf[((size_t)b * TT + tt) * DD + d0 + tx] = f2b(v);
    }
    __syncthreads();
#pragma unroll
    for (int u = 0; u < 4; ++u)
      tr_bf[((size_t)b * DD + d0 + ty + u * 8) * TP + t0 + tx] = f2b(t[tx][ty + u * 8]);
    return;
  }
  if (id < 16512) {  // ---- castb (cap -> bf16)
    int i = (id - 14464) * 256 + tid;
    if (i < 524288) {
      float4 v = *(const float4*)(cap + (size_t)i * 4);
      uint2 o;
      o.x = (unsigned int)f2b(v.x) | ((unsigned int)f2b(v.y) << 16);
      o.y = (unsigned int)f2b(v.z) | ((unsigned int)f2b(v.w) << 16);
      *(uint2*)(cap_bf + (size_t)i * 4) = o;
    }
    return;
  }
  if (id < 19264) {  // ---- tcast_all
    id -= 16512;
    const float* s;
    unsigned short* d;
    int R, C;
    if (id < 1024) {
      s = vWl; d = wlT_v; R = 1024; C = 1024;
    } else if (id < 2048) {
      s = tWl; d = wlT_t; R = 1024; C = 1024; id -= 1024;
    } else if (id < 2240) {
      id -= 2048;
      int tb = id >> 6; id &= 63;
      s = sWg + (size_t)tb * 65536; d = wgT3 + (size_t)tb * 65536; R = 256; C = 256;
    } else if (id < 2496) {
      s = Wloc; d = wlocT; R = 1024; C = 256; id -= 2240;
    } else {
      s = Wglo; d = wgloT; R = 1024; C = 256; id -= 2496;
    }
    float (*t)[33] = (float(*)[33])shbuf;
    int ct = C >> 5;
    int r0 = (id / ct) * 32, c0 = (id % ct) * 32;
    int tx = tid & 31, ty = tid >> 5;
#pragma unroll
    for (int u = 0; u < 4; ++u)
      t[ty + u * 8][tx] = s[(size_t)(r0 + ty + u * 8) * C + c0 + tx];
    __syncthreads();
#pragma unroll
    for (int u = 0; u < 4; ++u)
      d[(size_t)(c0 + ty + u * 8) * R + r0 + tx] = f2b(t[tx][ty + u * 8]);
    return;
  }
  // ---- mmatb (+wkbq fold): blocks 19264..19314
  id -= 19264;
  if (id >= 48) {  // wkbq
    int t = id - 48;
    float* bv = shbuf + 4352;
    const float* wk = Wb + (size_t)t * SS * SS;
    bv[tid] = bq[t * SS + tid];
    __syncthreads();
    float acc = 0.f;
    for (int j = 0; j < SS; j += 4) {
      float4 wv = *(const float4*)&wk[(size_t)tid * SS + j];
      float4 b4 = *(const float4*)&bv[j];
      acc += wv.x * b4.x + wv.y * b4.y + wv.z * b4.z + wv.w * b4.w;
    }
    wkbqv[t * SS + tid] = acc;
    return;
  }
  {
    float (*a_lds)[68] = (float(*)[68])shbuf;
    float (*b_lds)[68] = (float(*)[68])(shbuf + 2176);
    int t = id >> 4;
    int dt = (id >> 2) & 3, et = id & 3;
    int d0 = dt * 64, e0 = et * 64;
    const float* wq = Wa + (size_t)t * SS * SS;
    const float* wk = Wb + (size_t)t * SS * SS;
    int ty = tid >> 4, tx = tid & 15;
    int s_rr = tid >> 2, s_kq = tid & 3;
    float acc[4][4] = {};
    for (int j0 = 0; j0 < SS; j0 += 32) {
      float4 q0 = *(const float4*)&wq[(size_t)(d0 + s_rr) * SS + j0 + s_kq * 8];
      float4 q1 = *(const float4*)&wq[(size_t)(d0 + s_rr) * SS + j0 + s_kq * 8 + 4];
      float4 k0v = *(const float4*)&wk[(size_t)(e0 + s_rr) * SS + j0 + s_kq * 8];
      float4 k1v = *(const float4*)&wk[(size_t)(e0 + s_rr) * SS + j0 + s_kq * 8 + 4];
      __syncthreads();
      float qa[8] = {q0.x, q0.y, q0.z, q0.w, q1.x, q1.y, q1.z, q1.w};
      float ka[8] = {k0v.x, k0v.y, k0v.z, k0v.w, k1v.x, k1v.y, k1v.z, k1v.w};
#pragma unroll
      for (int u = 0; u < 8; ++u) {
        a_lds[s_kq * 8 + u][s_rr] = qa[u];
        b_lds[s_kq * 8 + u][s_rr] = ka[u];
      }
      __syncthreads();
#pragma unroll
      for (int kk = 0; kk < 32; ++kk) {
        float4 a4 = *(const float4*)&a_lds[kk][ty * 4];
        float4 b4 = *(const float4*)&b_lds[kk][tx * 4];
        float av[4] = {a4.x, a4.y, a4.z, a4.w};
        float bvv[4] = {b4.x, b4.y, b4.z, b4.w};
#pragma unroll
        for (int i = 0; i < 4; ++i)
#pragma unroll
          for (int j = 0; j < 4; ++j) acc[i][j] += av[i] * bvv[j];
      }
    }
#pragma unroll
    for (int i = 0; i < 4; ++i) {
      unsigned int lo = (unsigned int)f2b(acc[i][0]) | ((unsigned int)f2b(acc[i][1]) << 16);
      unsigned int hi = (unsigned int)f2b(acc[i][2]) | ((unsigned int)f2b(acc[i][3]) << 16);
      uint2 o = make_uint2(lo, hi);
      *(uint2*)(M + (size_t)t * SS * SS + (size_t)(d0 + ty * 4 + i) * SS + e0 + tx * 4) = o;
    }
  }
}

// ======== L2: hvec2 | gram_mfma (both depend only on L1) ========
__global__ void k_hvgram(const float* __restrict__ img_avg, const float* __restrict__ cap_avg,
                         const float* __restrict__ vWg, const float* __restrict__ vbg,
                         const float* __restrict__ vWc, const float* __restrict__ tWg,
                         const float* __restrict__ tbg, const float* __restrict__ tWc,
                         float* __restrict__ h_img, float* __restrict__ h_cap,
                         const unsigned short* __restrict__ img_bf,
                         unsigned short* __restrict__ gram) {
  __shared__ float av[DD];
  int id = blockIdx.x;
  int tid = threadIdx.x;
  if (id < 512) {
    const float* avg;
    const float* Wg;
    const float* bg;
    const float* Wc;
    float* h;
    if (id < 256) {
      avg = img_avg; Wg = vWg; bg = vbg; Wc = vWc; h = h_img;
    } else {
      avg = cap_avg; Wg = tWg; bg = tbg; Wc = tWc; h = h_cap; id -= 256;
    }
    int b = id >> 2;
    int dc = id & 3;
    for (int i = tid; i < DD; i += 256) av[i] = avg[b * DD + i];
    __syncthreads();
    int d = dc * 256 + tid;
    float acc = 0.f;
    for (int k = 0; k < DD; k += 4) {
      float4 a4 = *(const float4*)&av[k];
      acc += a4.x * Wg[(size_t)(k + 0) * DD + d];
      acc += a4.y * Wg[(size_t)(k + 1) * DD + d];
      acc += a4.z * Wg[(size_t)(k + 2) * DD + d];
      acc += a4.w * Wg[(size_t)(k + 3) * DD + d];
    }
    h[b * DD + d] = tanhf(acc + bg[d]) * Wc[d];
    return;
  }
  {
    int g = id - 512;
    int lane = tid & 63, w = tid >> 6;
    int lrow = lane & 15, lk = (lane >> 4) * 8, rsub = (lane >> 4) * 4;
    int bimg = g & 63;
    int rb = ((g >> 6) & 3) * 64, cb = (g >> 8) * 64;
    const unsigned short* X = img_bf + (size_t)bimg * TT * DD;
    int ra = rb + w * 16 + lrow;
    if (ra > TT - 1) ra = TT - 1;
    f32x4 acc[4] = {};
    for (int k0 = 0; k0 < DD; k0 += 32) {
      bfrag a = *(const bfrag*)(X + (size_t)ra * DD + k0 + lk);
#pragma unroll
      for (int i = 0; i < 4; ++i) {
        int cc = cb + i * 16 + lrow;
        if (cc > TT - 1) cc = TT - 1;
        bfrag bb = *(const bfrag*)(X + (size_t)cc * DD + k0 + lk);
        acc[i] = MFMA(a, bb, acc[i]);
      }
    }
    unsigned short* Gp = gram + (size_t)bimg * 208 * TP;
#pragma unroll
    for (int i = 0; i < 4; ++i) {
      int cc = cb + i * 16 + lrow;
#pragma unroll
      for (int r = 0; r < 4; ++r) {
        int rr = rb + w * 16 + rsub + r;
        if (rr < 208 && cc < TP)
          Gp[(size_t)rr * TP + cc] = (rr < TT && cc < TT) ? f2b(acc[i][r]) : 0;
      }
    }
  }
}

// ---------------- K3 (MFMA, merged img+cap): partial logits
__global__ void k_logits2(const unsigned short* __restrict__ Ai, const unsigned short* __restrict__ Wi,
                          const float* __restrict__ bli, const float* __restrict__ hi,
                          float* __restrict__ pi,
                          const unsigned short* __restrict__ Ac, const unsigned short* __restrict__ Wc2,
                          const float* __restrict__ blc, const float* __restrict__ hc,
                          float* __restrict__ pc) {
  int tid = threadIdx.x;
  int lane = tid & 63, w = tid >> 6;
  int lrow = lane & 15, lk = (lane >> 4) * 8, rsub = (lane >> 4) * 4;
  int bx = blockIdx.x;
  const unsigned short* Abf;
  const unsigned short* WT;
  const float* bl;
  const float* h;
  float* partial;
  int rb, rowsPerBatch;
  if (bx < 196) {
    Abf = Ai; WT = Wi; bl = bli; h = hi; partial = pi; rb = bx * 64; rowsPerBatch = TT;
  } else {
    Abf = Ac; WT = Wc2; bl = blc; h = hc; partial = pc; rb = (bx - 196) * 64; rowsPerBatch = CL;
  }
  int c0 = blockIdx.y * 64;
  const unsigned short* ap = Abf + (size_t)(rb + w * 16 + lrow) * DD;
  f32x4 acc[4] = {};
  for (int k0 = 0; k0 < DD; k0 += 32) {
    bfrag a = *(const bfrag*)(ap + k0 + lk);
#pragma unroll
    for (int i = 0; i < 4; ++i) {
      bfrag bb = *(const bfrag*)(WT + (size_t)(c0 + i * 16 + lrow) * DD + k0 + lk);
      acc[i] = MFMA(a, bb, acc[i]);
    }
  }
#pragma unroll
  for (int r = 0; r < 4; ++r) {
    int row = rb + w * 16 + rsub + r;
    int bb2 = row / rowsPerBatch;
    float s = 0.f;
#pragma unroll
    for (int i = 0; i < 4; ++i) {
      int col = c0 + i * 16 + lrow;
      s += tanhf(acc[i][r] + bl[col]) * h[bb2 * DD + col];
    }
    s += __shfl_xor(s, 1, 64);
    s += __shfl_xor(s, 2, 64);
    s += __shfl_xor(s, 4, 64);
    s += __shfl_xor(s, 8, 64);
    if (lrow == 0) partial[(size_t)row * 16 + blockIdx.y] = s;
  }
}

// -------- K4 (merged img+cap): finish global attention pooling
__global__ void k_finish2(const float* __restrict__ pi, const float* __restrict__ bci,
                          const float* __restrict__ Xi, long bsi, int Ri, float* __restrict__ oi,
                          const float* __restrict__ pc, const float* __restrict__ bcc,
                          const float* __restrict__ Xc, long bsc, int Rc, float* __restrict__ oc) {
  __shared__ float w[200];
  __shared__ float red[8];
  int bid = blockIdx.x, tid = threadIdx.x;
  const float* partial;
  const float* bc;
  const float* Xbase;
  long batchStride;
  int R, b;
  float* outG;
  if (bid < 64) {
    partial = pi; bc = bci; Xbase = Xi; batchStride = bsi; R = Ri; outG = oi; b = bid;
  } else {
    partial = pc; bc = bcc; Xbase = Xc; batchStride = bsc; R = Rc; outG = oc; b = bid - 64;
  }
  for (int t = tid; t < R; t += 256) {
    const float* pp = &partial[((size_t)b * R + t) * 16];
    float s = bc[0];
#pragma unroll
    for (int u = 0; u < 16; ++u) s += pp[u];
    w[t] = s;
  }
  __syncthreads();
  float m = -1e30f;
  for (int t = tid; t < R; t += 256) m = fmaxf(m, w[t]);
#pragma unroll
  for (int mm = 32; mm; mm >>= 1) m = fmaxf(m, __shfl_xor(m, mm, 64));
  if ((tid & 63) == 0) red[tid >> 6] = m;
  __syncthreads();
  m = fmaxf(fmaxf(red[0], red[1]), fmaxf(red[2], red[3]));
  __syncthreads();
  for (int t = tid; t < R; t += 256) w[t] = expf(w[t] - m);
  __syncthreads();
  const float* xb = Xbase + (size_t)b * batchStride;
  float acc[4];
  float ss = 0.f;
#pragma unroll
  for (int c4 = 0; c4 < 4; ++c4) {
    int d = tid + c4 * 256;
    float a = 0.f;
    for (int t = 0; t < R; ++t) a += w[t] * xb[(size_t)t * DD + d];
    acc[c4] = a;
    ss += a * a;
  }
  ss = warp_reduce_sum64(ss);
  if ((tid & 63) == 0) red[tid >> 6] = ss;
  __syncthreads();
  ss = red[0] + red[1] + red[2] + red[3];
  float rn = 1.0f / fmaxf(sqrtf(ss), EPSN);
#pragma unroll
  for (int c4 = 0; c4 < 4; ++c4) outG[(size_t)b * DD + tid + c4 * 256] = acc[c4] * rn;
}

// -------- K5 (MFMA): sim_glo
__global__ void k_simglo_m(const float* __restrict__ ig, const float* __restrict__ cg,
                           const unsigned short* __restrict__ wgloT,
                           const float* __restrict__ bgl, float* __restrict__ simglo) {
  __shared__ unsigned short aL[64 * 40];
  int tid = threadIdx.x;
  int lane = tid & 63, w = tid >> 6;
  int lrow = lane & 15, lk = (lane >> 4) * 8, rsub = (lane >> 4) * 4;
  int b = blockIdx.x;
  int srow = tid >> 2, skq = tid & 3;
  f32x4 acc[16] = {};
  for (int k0 = 0; k0 < DD; k0 += 32) {
    const float* ip = ig + (size_t)b * DD + k0 + skq * 8;
    const float* cp = cg + (size_t)srow * DD + k0 + skq * 8;
    float4 i0 = *(const float4*)ip;
    float4 i1 = *(const float4*)(ip + 4);
    float4 c0 = *(const float4*)cp;
    float4 c1 = *(const float4*)(cp + 4);
    float d0 = i0.x - c0.x, d1 = i0.y - c0.y, d2 = i0.z - c0.z, d3 = i0.w - c0.w;
    float d4 = i1.x - c1.x, d5 = i1.y - c1.y, d6 = i1.z - c1.z, d7 = i1.w - c1.w;
    uint4 o;
    o.x = (unsigned int)f2b(d0 * d0) | ((unsigned int)f2b(d1 * d1) << 16);
    o.y = (unsigned int)f2b(d2 * d2) | ((unsigned int)f2b(d3 * d3) << 16);
    o.z = (unsigned int)f2b(d4 * d4) | ((unsigned int)f2b(d5 * d5) << 16);
    o.w = (unsigned int)f2b(d6 * d6) | ((unsigned int)f2b(d7 * d7) << 16);
    __syncthreads();
    *(uint4*)&aL[srow * 40 + skq * 8] = o;
    __syncthreads();
    bfrag af = *(const bfrag*)&aL[(w * 16 + lrow) * 40 + lk];
#pragma unroll
    for (int ct = 0; ct < 16; ++ct) {
      bfrag bb = *(const bfrag*)(wgloT + (size_t)(ct * 16 + lrow) * DD + k0 + lk);
      acc[ct] = MFMA(af, bb, acc[ct]);
    }
  }
  float bglv[16];
#pragma unroll
  for (int ct = 0; ct < 16; ++ct) bglv[ct] = bgl[ct * 16 + lrow];
#pragma unroll
  for (int r = 0; r < 4; ++r) {
    int crow = w * 16 + rsub + r;
    float vv[16];
    float ssq = 0.f;
#pragma unroll
    for (int ct = 0; ct < 16; ++ct) {
      float v = acc[ct][r] + bglv[ct];
      vv[ct] = v;
      ssq += v * v;
    }
    ssq += __shfl_xor(ssq, 1, 64);
    ssq += __shfl_xor(ssq, 2, 64);
    ssq += __shfl_xor(ssq, 4, 64);
    ssq += __shfl_xor(ssq, 8, 64);
    float rn = 1.0f / fmaxf(sqrtf(ssq), EPSN);
    float* op = simglo + ((size_t)b * 64 + crow) * SS;
#pragma unroll
    for (int ct = 0; ct < 16; ++ct) op[ct * 16 + lrow] = vv[ct] * rn;
  }
}

// -------- K7: per-(img,cap) pair mega kernel (v12: SGR X/O barriers removed)
__global__ __launch_bounds__(256, 4) void k_pair(
    const float* __restrict__ b_loc, const float* __restrict__ simglo,
    const float* __restrict__ wkbq, const float* __restrict__ bg3,
    const float* __restrict__ W_eval, const float* __restrict__ b_eval,
    const unsigned short* __restrict__ cap_bf, const unsigned short* __restrict__ img_bf,
    const unsigned short* __restrict__ imgT_bf, const unsigned short* __restrict__ gram_bf,
    const unsigned short* __restrict__ wlocT_bf, const unsigned short* __restrict__ mt_bf,
    const unsigned short* __restrict__ wgT_bf, float* __restrict__ out) {
  extern __shared__ char smem[];

  int tid = threadIdx.x;
  int lane = tid & 63, w = tid >> 6;
  int lrow = lane & 15;
  int lk = (lane >> 4) * 8;
  int rsub = (lane >> 4) * 4;
  int p = ((blockIdx.x & 7) << 9) | (blockIdx.x >> 3);  // XCD-contiguous pair blocks
  int b = p >> 6, c = p & 63;
  const unsigned short* imgR = img_bf + (size_t)b * TT * DD;
  const unsigned short* capB = cap_bf + (size_t)c * CL * DD;
  char* attnT_b = smem + OFF_ATTNT;

  // ================ Phase A
  {
    f32x4 acc[4][2] = {};
    for (int k0 = 0; k0 < DD; k0 += 32) {
      bfrag bq0 = *(const bfrag*)(capB + (size_t)lrow * DD + k0 + lk);
      bfrag bq1 = *(const bfrag*)(capB + (size_t)(16 + lrow) * DD + k0 + lk);
#pragma unroll
      for (int i = 0; i < 4; ++i) {
        int tt = w + 4 * i;
        if (tt < 13) {
          int t = tt * 16 + lrow;
          bfrag a = {0, 0, 0, 0, 0, 0, 0, 0};
          if (t < TT) a = *(const bfrag*)(imgR + (size_t)t * DD + k0 + lk);
          acc[i][0] = MFMA(a, bq0, acc[i][0]);
          acc[i][1] = MFMA(a, bq1, acc[i][1]);
        }
      }
    }
    float mx0 = -1e30f, mx1 = -1e30f;
#pragma unroll
    for (int i = 0; i < 4; ++i) {
      int tt = w + 4 * i;
      if (tt < 13) {
#pragma unroll
        for (int r = 0; r < 4; ++r) {
          int t = tt * 16 + rsub + r;
          float v0 = acc[i][0][r];
          v0 = v0 < 0.f ? 0.1f * v0 : v0;
          float v1 = acc[i][1][r];
          v1 = v1 < 0.f ? 0.1f * v1 : v1;
          float s2 = v0 * v0 + v1 * v1;
          s2 += __shfl_xor(s2, 1, 64);
          s2 += __shfl_xor(s2, 2, 64);
          s2 += __shfl_xor(s2, 4, 64);
          s2 += __shfl_xor(s2, 8, 64);
          float rn = 1.0f / fmaxf(sqrtf(s2), EPSN);
          v0 *= rn;
          v1 *= rn;
          acc[i][0][r] = v0;
          acc[i][1][r] = v1;
          if (t < TT) {
            mx0 = fmaxf(mx0, v0);
            mx1 = fmaxf(mx1, v1);
          }
        }
      }
    }
    mx0 = fmaxf(mx0, __shfl_xor(mx0, 16, 64));
    mx0 = fmaxf(mx0, __shfl_xor(mx0, 32, 64));
    mx1 = fmaxf(mx1, __shfl_xor(mx1, 16, 64));
    mx1 = fmaxf(mx1, __shfl_xor(mx1, 32, 64));
    float* wmax = (float*)(smem + OFF_WMAX);
    if ((lane >> 4) == 0) {
      wmax[w * 32 + lrow] = mx0;
      wmax[w * 32 + 16 + lrow] = mx1;
    }
    __syncthreads();
    mx0 = fmaxf(fmaxf(wmax[lrow], wmax[32 + lrow]), fmaxf(wmax[64 + lrow], wmax[96 + lrow]));
    mx1 = fmaxf(fmaxf(wmax[16 + lrow], wmax[48 + lrow]),
                fmaxf(wmax[80 + lrow], wmax[112 + lrow]));
#pragma unroll
    for (int i = 0; i < 4; ++i) {
      int tt = w + 4 * i;
#pragma unroll
      for (int r = 0; r < 4; ++r) {
        int t = tt * 16 + rsub + r;
        if (t < TP) {
          unsigned short e0 = 0, e1 = 0;
          if (t < TT) {
            e0 = f2b(expf(SMOOTHF * (acc[i][0][r] - mx0)));
            e1 = f2b(expf(SMOOTHF * (acc[i][1][r] - mx1)));
          }
          *(unsigned short*)(attnT_b + lrow * 464 + t * 2) = e0;
          *(unsigned short*)(attnT_b + (16 + lrow) * 464 + t * 2) = e1;
        }
      }
    }
  }
  __syncthreads();

  // ================ norm via Gram (MFMA)
  {
    float* qn = (float*)(smem + OFF_QN);
    float* nrmS = (float*)(smem + OFF_NRMS);
    const unsigned short* gb = gram_bf + (size_t)b * 208 * TP;
    float part0 = 0.f, part1 = 0.f;
#pragma unroll
    for (int i = 0; i < 4; ++i) {
      int tt = w + 4 * i;
      if (tt < 13) {
        f32x4 y0 = {0.f, 0.f, 0.f, 0.f}, y1 = {0.f, 0.f, 0.f, 0.f};
        for (int t0 = 0; t0 < TP; t0 += 32) {
          bfrag a = *(const bfrag*)(gb + (size_t)(tt * 16 + lrow) * TP + t0 + lk);
          bfrag b0 = *(const bfrag*)(attnT_b + lrow * 464 + (t0 + lk) * 2);
          bfrag b1 = *(const bfrag*)(attnT_b + (16 + lrow) * 464 + (t0 + lk) * 2);
          y0 = MFMA(a, b0, y0);
          y1 = MFMA(a, b1, y1);
        }
#pragma unroll
        for (int r = 0; r < 4; ++r) {
          int t = tt * 16 + rsub + r;
          if (t < TT) {
            part0 += y0[r] * b2f(*(const unsigned short*)(attnT_b + lrow * 464 + t * 2));
            part1 += y1[r] * b2f(*(const unsigned short*)(attnT_b + (16 + lrow) * 464 + t * 2));
          }
        }
      }
    }
    part0 += __shfl_xor(part0, 16, 64);
    part0 += __shfl_xor(part0, 32, 64);
    part1 += __shfl_xor(part1, 16, 64);
    part1 += __shfl_xor(part1, 32, 64);
    if ((lane >> 4) == 0) {
      qn[w * 32 + lrow] = part0;
      qn[w * 32 + 16 + lrow] = part1;
    }
    __syncthreads();
    if (tid < 32)
      nrmS[tid] = 1.0f / fmaxf(sqrtf(qn[tid] + qn[32 + tid] + qn[64 + tid] + qn[96 + tid]), EPSN);
    __syncthreads();
  }

  // ================ Phase W
  f32x4 accW[2][4] = {};
  {
    char* wtile_b = smem + OFF_WTILE;
    float* nrmS = (float*)(smem + OFF_NRMS);
    float nrm0 = nrmS[lrow], nrm1 = nrmS[16 + lrow];
    for (int d0 = 0; d0 < DD; d0 += 128) {
#pragma unroll
      for (int i = 0; i < 2; ++i) {
        f32x4 c2[2] = {};
        int dt = w + 4 * i;
        const unsigned short* ib = imgT_bf + ((size_t)b * DD + d0 + dt * 16 + lrow) * TP;
        for (int t0 = 0; t0 < TP; t0 += 32) {
          bfrag b0 = *(const bfrag*)(attnT_b + lrow * 464 + (t0 + lk) * 2);
          bfrag b1 = *(const bfrag*)(attnT_b + (16 + lrow) * 464 + (t0 + lk) * 2);
          bfrag a = *(const bfrag*)(ib + t0 + lk);
          c2[0] = MFMA(a, b0, c2[0]);
          c2[1] = MFMA(a, b1, c2[1]);
        }
        if (i == 0) __syncthreads();
        int dl = dt * 16 + rsub;
#pragma unroll
        for (int qt = 0; qt < 2; ++qt) {
          int q = qt * 16 + lrow;
          uint2 cu = *(const uint2*)(capB + (size_t)q * DD + d0 + dl);
          float cf0 = b2f(cu.x & 0xffff), cf1 = b2f(cu.x >> 16);
          float cf2 = b2f(cu.y & 0xffff), cf3 = b2f(cu.y >> 16);
          float rn = qt ? nrm1 : nrm0;
          float v0 = c2[qt][0] * rn - cf0;
          float v1 = c2[qt][1] * rn - cf1;
          float v2 = c2[qt][2] * rn - cf2;
          float v3 = c2[qt][3] * rn - cf3;
          unsigned int lo = (unsigned int)f2b(v0 * v0) | ((unsigned int)f2b(v1 * v1) << 16);
          unsigned int hi = (unsigned int)f2b(v2 * v2) | ((unsigned int)f2b(v3 * v3) << 16);
          *(uint2*)(wtile_b + q * 272 + dl * 2) = make_uint2(lo, hi);
        }
      }
      __syncthreads();
      for (int kc = 0; kc < 4; ++kc) {
        bfrag a0 = *(const bfrag*)(wtile_b + lrow * 272 + (kc * 32 + lk) * 2);
        bfrag a1 = *(const bfrag*)(wtile_b + (16 + lrow) * 272 + (kc * 32 + lk) * 2);
#pragma unroll
        for (int sti = 0; sti < 4; ++sti) {
          int s = (w * 4 + sti) * 16 + lrow;
          bfrag bb = *(const bfrag*)(wlocT_bf + (size_t)s * DD + d0 + kc * 32 + lk);
          accW[0][sti] = MFMA(a0, bb, accW[0][sti]);
          accW[1][sti] = MFMA(a1, bb, accW[1][sti]);
        }
      }
    }
  }

  // ================ assembly
  {
    char* seA_b = smem + OFF_SEA;
    float* qn = (float*)(smem + OFF_QN);
    float* rnq = (float*)(smem + OFF_RNQ);
    __syncthreads();
    float blv[4];
#pragma unroll
    for (int sti = 0; sti < 4; ++sti) blv[sti] = b_loc[(w * 4 + sti) * 16 + lrow];
    float ss[2][4];
#pragma unroll
    for (int qt = 0; qt < 2; ++qt)
#pragma unroll
      for (int r = 0; r < 4; ++r) {
        float s2 = 0.f;
#pragma unroll
        for (int sti = 0; sti < 4; ++sti) {
          float v = accW[qt][sti][r] + blv[sti];
          s2 += v * v;
        }
        s2 += __shfl_xor(s2, 1, 64);
        s2 += __shfl_xor(s2, 2, 64);
        s2 += __shfl_xor(s2, 4, 64);
        s2 += __shfl_xor(s2, 8, 64);
        ss[qt][r] = s2;
      }
    if (lrow == 0) {
#pragma unroll
      for (int qt = 0; qt < 2; ++qt)
#pragma unroll
        for (int r = 0; r < 4; ++r)
          qn[w * 32 + qt * 16 + rsub + r] = ss[qt][r];
    }
    __syncthreads();
    if (tid < 32)
      rnq[tid] = 1.0f / fmaxf(sqrtf(qn[tid] + qn[32 + tid] + qn[64 + tid] + qn[96 + tid]), EPSN);
    __syncthreads();
#pragma unroll
    for (int qt = 0; qt < 2; ++qt)
#pragma unroll
      for (int r = 0; r < 4; ++r) {
        int q = qt * 16 + rsub + r;
        float rn = rnq[q];
#pragma unroll
        for (int sti = 0; sti < 4; ++sti) {
          int s = (w * 4 + sti) * 16 + lrow;
          float v = (accW[qt][sti][r] + blv[sti]) * rn;
          *(unsigned short*)(seA_b + (1 + q) * 528 + s * 2) = f2b(v);
        }
      }
    if (tid < 64) {
      float4 g4 = *(const float4*)&simglo[(size_t)p * SS + tid * 4];
      unsigned int lo = (unsigned int)f2b(g4.x) | ((unsigned int)f2b(g4.y) << 16);
      unsigned int hi = (unsigned int)f2b(g4.z) | ((unsigned int)f2b(g4.w) << 16);
      *(uint2*)(seA_b + tid * 8) = make_uint2(lo, hi);
    }
    __syncthreads();
  }

  // ================ SGR x3
  {
    char* seA_b = smem + OFF_SEA;
    char* Gc_b = smem + OFF_R1;
    char* XT_b = smem + OFF_R1;
    float* Ef = (float*)(smem + OFF_R1);
    char* Eb = smem + OFF_EB;
    float* wkq = (float*)(smem + OFF_WKQ);
    float* vbuf = (float*)(smem + OFF_VBUF);

    for (int step = 0; step < 3; ++step) {
      const unsigned short* mstep = mt_bf + (size_t)step * SS * SS;
      const unsigned short* wstep = wgT_bf + (size_t)step * SS * SS;
      wkq[tid] = wkbq[step * SS + tid];
      __syncthreads();
      if (tid < 132) {
        int m = tid >> 2, qq = tid & 3;
        float a = 0.f;
        for (int e = qq * 64; e < qq * 64 + 64; e += 2) {
          unsigned int u = *(const unsigned int*)(seA_b + m * 528 + e * 2);
          a += b2f(u & 0xffff) * wkq[e] + b2f(u >> 16) * wkq[e + 1];
        }
        a += __shfl_xor(a, 1, 64);
        a += __shfl_xor(a, 2, 64);
        if (qq == 0) vbuf[m] = a;
      }
      f32x4 aE[3] = {};
      for (int ec = 0; ec < 4; ++ec) {
        f32x4 aGc[3] = {};
        for (int kc = 0; kc < 8; ++kc) {
          int k = kc * 32 + lk;
          bfrag bb = *(const bfrag*)(mstep + (size_t)(ec * 64 + w * 16 + lrow) * SS + k);
#pragma unroll
          for (int mt = 0; mt < 3; ++mt) {
            bfrag af = *(const bfrag*)(seA_b + (mt * 16 + lrow) * 528 + k * 2);
            aGc[mt] = MFMA(af, bb, aGc[mt]);
          }
        }
        __syncthreads();  // prior chunk's Gc readers done (cross-wave)
#pragma unroll
        for (int mt = 0; mt < 3; ++mt)
#pragma unroll
          for (int r = 0; r < 4; ++r)
            *(unsigned short*)(Gc_b + (mt * 16 + rsub + r) * 144 + (w * 16 + lrow) * 2) =
                f2b(aGc[mt][r]);
        __syncthreads();
#pragma unroll
        for (int kc = 0; kc < 2; ++kc) {
          int k = kc * 32 + lk;
#pragma unroll
          for (int ti = 0; ti < 3; ++ti) {
            int tile = w + ti * 4;
            if (tile < 9) {
              int mtE = tile / 3, ntE = tile - mtE * 3;
              bfrag ga = *(const bfrag*)(Gc_b + (mtE * 16 + lrow) * 144 + k * 2);
              bfrag sb = *(const bfrag*)(seA_b + (ntE * 16 + lrow) * 528 + (ec * 64 + k) * 2);
              aE[ti] = MFMA(ga, sb, aE[ti]);
            }
          }
        }
      }
      __syncthreads();  // all Gc reads done before Ef overlays it
#pragma unroll
      for (int ti = 0; ti < 3; ++ti) {
        int tile = w + ti * 4;
        if (tile < 9) {
          int mtE = tile / 3, ntE = tile - mtE * 3;
          int n0 = mtE * 16 + rsub, m = ntE * 16 + lrow;
#pragma unroll
          for (int r = 0; r < 4; ++r)
            if (n0 + r < NN && m < NN) Ef[(n0 + r) * 34 + m] = aE[ti][r] + vbuf[m];
        }
      }
      __syncthreads();
      if (tid < NN) {
        float mx = -1e30f;
        for (int mm = 0; mm < NN; ++mm) mx = fmaxf(mx, Ef[tid * 34 + mm]);
        float sum = 0.f;
        for (int mm = 0; mm < NN; ++mm) {
          float e = expf(Ef[tid * 34 + mm] - mx);
          Ef[tid * 34 + mm] = e;
          sum += e;
        }
        float rs = 1.0f / sum;
        for (int mm = 0; mm < NN; ++mm) Ef[tid * 34 + mm] *= rs;
      }
      __syncthreads();
      for (int idx = tid; idx < 33 * 36; idx += 256) {
        int n = idx / 36, mp = (idx - n * 36) * 2;
        unsigned int lo = (mp < NN) ? (unsigned int)f2b(Ef[n * 34 + mp]) : 0u;
        unsigned int hi = (mp + 1 < NN) ? (unsigned int)f2b(Ef[n * 34 + mp + 1]) : 0u;
        *(unsigned int*)(Eb + n * 144 + mp * 2) = lo | (hi << 16);
      }
      __syncthreads();  // Eb ready; Ef dead -> XT may overlay
      // XT rows are PER-WAVE private (store row w*16+lrow, read row w*16+lrow):
      // no cross-wave flow -> no barriers inside the sc loop.
      *(uint2*)(XT_b + (w * 16 + lrow) * 144 + (48 + rsub) * 2) = make_uint2(0, 0);
      unsigned int oPk[4][3][2];
#pragma unroll
      for (int sc = 0; sc < 4; ++sc) {
        f32x4 aX[3] = {};
        for (int kc = 0; kc < 8; ++kc) {
          int k = kc * 32 + lk;
          bfrag bb = *(const bfrag*)(wstep + (size_t)(sc * 64 + w * 16 + lrow) * SS + k);
#pragma unroll
          for (int mt = 0; mt < 3; ++mt) {
            bfrag af = *(const bfrag*)(seA_b + (mt * 16 + lrow) * 528 + k * 2);
            aX[mt] = MFMA(af, bb, aX[mt]);
          }
        }
#pragma unroll
        for (int mt = 0; mt < 3; ++mt) {
          unsigned int lo = (unsigned int)f2b(aX[mt][0]) | ((unsigned int)f2b(aX[mt][1]) << 16);
          unsigned int hi = (unsigned int)f2b(aX[mt][2]) | ((unsigned int)f2b(aX[mt][3]) << 16);
          *(uint2*)(XT_b + (w * 16 + lrow) * 144 + (mt * 16 + rsub) * 2) = make_uint2(lo, hi);
        }
        f32x4 aO[3] = {};
#pragma unroll
        for (int kc = 0; kc < 2; ++kc) {
          int k = kc * 32 + lk;
          bfrag xa = *(const bfrag*)(XT_b + (w * 16 + lrow) * 144 + k * 2);
#pragma unroll
          for (int nt = 0; nt < 3; ++nt) {
            bfrag eb = *(const bfrag*)(Eb + (nt * 16 + lrow) * 144 + k * 2);
            aO[nt] = MFMA(xa, eb, aO[nt]);
          }
        }
        float bga[4];
#pragma unroll
        for (int r = 0; r < 4; ++r) bga[r] = bg3[step * SS + sc * 64 + w * 16 + rsub + r];
#pragma unroll
        for (int nt = 0; nt < 3; ++nt) {
          float v0 = fmaxf(aO[nt][0] + bga[0], 0.f);
          float v1 = fmaxf(aO[nt][1] + bga[1], 0.f);
          float v2 = fmaxf(aO[nt][2] + bga[2], 0.f);
          float v3 = fmaxf(aO[nt][3] + bga[3], 0.f);
          oPk[sc][nt][0] = (unsigned int)f2b(v0) | ((unsigned int)f2b(v1) << 16);
          oPk[sc][nt][1] = (unsigned int)f2b(v2) | ((unsigned int)f2b(v3) << 16);
        }
      }
#pragma unroll
      for (int sc = 0; sc < 4; ++sc)
#pragma unroll
        for (int nt = 0; nt < 3; ++nt) {
          int n = nt * 16 + lrow;
          if (n < NN)
            *(uint2*)(seA_b + n * 528 + (sc * 64 + w * 16 + rsub) * 2) =
                make_uint2(oPk[sc][nt][0], oPk[sc][nt][1]);
        }
      __syncthreads();
    }
  }

  // ================ eval
  if (tid < 64) {
    const char* seA_b = smem + OFF_SEA;
    uint2 u = *(const uint2*)(seA_b + tid * 8);
    float4 w4 = *(const float4*)&W_eval[tid * 4];
    float s = b2f(u.x & 0xffff) * w4.x + b2f(u.x >> 16) * w4.y +
              b2f(u.y & 0xffff) * w4.z + b2f(u.y >> 16) * w4.w;
    s = warp_reduce_sum64(s);
    if (tid == 0) out[b * 64 + c] = 1.0f / (1.0f + expf(-(s + b_eval[0])));
  }
}

extern "C" void kernel_launch(void* const* d_in, const int* in_sizes, int n_in,
                              void* d_out, int out_size, void* d_ws, size_t ws_size,
                              hipStream_t stream) {
  (void)in_sizes; (void)n_in; (void)out_size; (void)ws_size;
  const float* img = (const float*)d_in[0];
  const float* cap = (const float*)d_in[1];
  const float* vG_Wl = (const float*)d_in[3];
  const float* vG_bl = (const float*)d_in[4];
  const float* vG_Wg = (const float*)d_in[5];
  const float* vG_bg = (const float*)d_in[6];
  const float* vG_Wc = (const float*)d_in[7];
  const float* vG_bc = (const float*)d_in[8];
  const float* tG_Wl = (const float*)d_in[9];
  const float* tG_bl = (const float*)d_in[10];
  const float* tG_Wg = (const float*)d_in[11];
  const float* tG_bg = (const float*)d_in[12];
  const float* tG_Wc = (const float*)d_in[13];
  const float* tG_bc = (const float*)d_in[14];
  const float* W_loc = (const float*)d_in[15];
  const float* b_loc = (const float*)d_in[16];
  const float* W_glo = (const float*)d_in[17];
  const float* b_glo = (const float*)d_in[18];
  const float* W_eval = (const float*)d_in[19];
  const float* b_eval = (const float*)d_in[20];
  const float* sgr_Wq = (const float*)d_in[21];
  const float* sgr_bq = (const float*)d_in[22];
  const float* sgr_Wk = (const float*)d_in[23];
  const float* sgr_Wg = (const float*)d_in[25];
  const float* sgr_bg = (const float*)d_in[26];
  float* out = (float*)d_out;
  float* ws = (float*)d_ws;
  float* img_avg = ws;
  float* cap_avg = ws + 65536;
  float* h_img = ws + 131072;
  float* h_cap = ws + 196608;
  float* part_img = ws + 262144;
  float* part_cap = ws + 462848;
  float* img_glob = ws + 495616;
  float* cap_glob = ws + 561152;
  float* simglo = ws + 626688;
  float* wkbqv = ws + 1675264;
  // bf16 region (u16 units) starts at float offset 1676032 (16B aligned)
  unsigned short* ub = (unsigned short*)(ws + 1676032);
  unsigned short* mt_bf = ub;                   // 196608
  unsigned short* wgT_bf = ub + 196608;         // 196608 -> 393216
  unsigned short* wlocT_bf = ub + 393216;       // 262144 -> 655360
  unsigned short* cap_bf = ub + 655360;         // 2097152 -> 2752512
  unsigned short* gram_bf = ub + 2752512;       // 2981888 -> 5734400
  unsigned short* imgT_bf = ub + 5734400;       // 14680064 -> 20414464
  unsigned short* img_bf = ub + 20414464;       // 12845056 -> 33259520
  unsigned short* wlT_v = ub + 33259520;        // 1048576 -> 34308096
  unsigned short* wlT_t = ub + 34308096;        // 1048576 -> 35356672
  unsigned short* wgloT = ub + 35356672;        // 262144 -> 35618816

  k_prep<<<19315, 256, 0, stream>>>(img, cap, img_avg, cap_avg, img_bf, imgT_bf, cap_bf,
                                    vG_Wl, tG_Wl, sgr_Wg, W_loc, W_glo,
                                    wlT_v, wlT_t, wgT_bf, wlocT_bf, wgloT,
                                    sgr_Wk, sgr_Wq, mt_bf, sgr_bq, wkbqv);
  k_hvgram<<<1536, 256, 0, stream>>>(img_avg, cap_avg, vG_Wg, vG_bg, vG_Wc,
                                     tG_Wg, tG_bg, tG_Wc, h_img, h_cap, img_bf, gram_bf);
  k_logits2<<<dim3(228, 16), 256, 0, stream>>>(img_bf, wlT_v, vG_bl, h_img, part_img,
                                               cap_bf, wlT_t, tG_bl, h_cap, part_cap);
  k_finish2<<<128, 256, 0, stream>>>(part_img, vG_bc, img + DD, (long)NTOK * DD, TT, img_glob,
                                     part_cap, tG_bc, cap, (long)CL * DD, CL, cap_glob);
  k_simglo_m<<<64, 256, 0, stream>>>(img_glob, cap_glob, wgloT, b_glo, simglo);
  hipFuncSetAttribute((const void*)k_pair, hipFuncAttributeMaxDynamicSharedMemorySize,
                      SMEM_BYTES);
  k_pair<<<4096, 256, SMEM_BYTES, stream>>>(b_loc, simglo, wkbqv, sgr_bg, W_eval, b_eval,
                                            cap_bf, img_bf, imgT_bf, gram_bf, wlocT_bf,
                                            mt_bf, wgT_bf, out);
}